// Round 2
// baseline (672.359 us; speedup 1.0000x reference)
//
#include <hip/hip_runtime.h>
#include <hip/hip_bf16.h>
#include <stdint.h>

typedef _Float16 f16;
typedef _Float16 half4 __attribute__((ext_vector_type(4)));

// ---------------- CSR build ----------------

__global__ void k_zero_int(int* __restrict__ p, int n) {
    int i = blockIdx.x * blockDim.x + threadIdx.x;
    if (i < n) p[i] = 0;
}

__global__ void k_count(const int* __restrict__ dst, int E, int* __restrict__ cnt) {
    int e = blockIdx.x * blockDim.x + threadIdx.x;
    if (e < E) atomicAdd(&cnt[dst[e]], 1);
}

// single block, 1024 threads: exclusive scan of cnt -> row_ptr/cursor, dinv = rsqrt(deg+1)
__global__ void k_scan(const int* __restrict__ cnt, int n, int E,
                       int* __restrict__ row_ptr, int* __restrict__ cursor,
                       float* __restrict__ dinv) {
    const int T = 1024;
    int tid = threadIdx.x;
    int seg = (n + T - 1) / T;
    int lo = tid * seg;
    int hi = min(lo + seg, n);
    int s = 0;
    for (int i = lo; i < hi; i++) s += cnt[i];

    __shared__ int wsum[16];
    int lane = tid & 63, wid = tid >> 6;
    int v = s;
    for (int off = 1; off < 64; off <<= 1) {
        int u = __shfl_up(v, off);
        if (lane >= off) v += u;
    }
    if (lane == 63) wsum[wid] = v;
    __syncthreads();
    if (wid == 0) {
        int wv = (lane < 16) ? wsum[lane] : 0;
        for (int off = 1; off < 16; off <<= 1) {
            int u = __shfl_up(wv, off);
            if (lane >= off) wv += u;
        }
        if (lane < 16) wsum[lane] = wv;
    }
    __syncthreads();
    int base = ((wid > 0) ? wsum[wid - 1] : 0) + (v - s);  // exclusive prefix of this thread
    int run = base;
    for (int i = lo; i < hi; i++) {
        row_ptr[i] = run;
        cursor[i] = run;
        int c = cnt[i];
        dinv[i] = rsqrtf((float)(c + 1));  // +1 self loop, deg always > 0
        run += c;
    }
    if (tid == 0) row_ptr[n] = E;
}

__global__ void k_fill(const int* __restrict__ src, const int* __restrict__ dst, int E,
                       int* __restrict__ cursor, int* __restrict__ ssorted) {
    int e = blockIdx.x * blockDim.x + threadIdx.x;
    if (e < E) {
        int p = atomicAdd(&cursor[dst[e]], 1);
        ssorted[p] = src[e];
    }
}

// ---------------- GEMM1: h1_pre[n,64] = x[n,256] @ W_enc_gnn[256,64] (fp32) ---------

#define G1_R 16
__global__ __launch_bounds__(256) void k_gemm1(const float* __restrict__ x,
                                               const float* __restrict__ W,
                                               float* __restrict__ out, int n) {
    __shared__ f16 Wh[256 * 64];     // 32 KB
    __shared__ float As[G1_R * 257]; // padded rows, 16.4 KB
    int tid = threadIdx.x;
    for (int i = tid * 4; i < 256 * 64; i += 1024) {
        float4 w = *(const float4*)&W[i];
        Wh[i + 0] = (f16)w.x;
        Wh[i + 1] = (f16)w.y;
        Wh[i + 2] = (f16)w.z;
        Wh[i + 3] = (f16)w.w;
    }
    int row0 = blockIdx.x * G1_R;
    for (int i4 = tid; i4 < G1_R * 64; i4 += 256) {  // 64 float4 per row
        int r = i4 >> 6, k4 = (i4 & 63) * 4;
        int gr = row0 + r;
        float4 xx = {0.f, 0.f, 0.f, 0.f};
        if (gr < n) xx = *(const float4*)&x[(size_t)gr * 256 + k4];
        As[r * 257 + k4 + 0] = xx.x;
        As[r * 257 + k4 + 1] = xx.y;
        As[r * 257 + k4 + 2] = xx.z;
        As[r * 257 + k4 + 3] = xx.w;
    }
    __syncthreads();
    int r = tid >> 4;          // 0..15
    int cg = (tid & 15) * 4;   // col group
    float4 acc = {0.f, 0.f, 0.f, 0.f};
    const float* ap = &As[r * 257];
#pragma unroll 4
    for (int k = 0; k < 256; k++) {
        float a = ap[k];
        half4 w = *(const half4*)&Wh[k * 64 + cg];
        acc.x += a * (float)w.x;
        acc.y += a * (float)w.y;
        acc.z += a * (float)w.z;
        acc.w += a * (float)w.w;
    }
    int gr = row0 + r;
    if (gr < n) *(float4*)&out[(size_t)gr * 64 + cg] = acc;
}

// ---------------- propagation: out[d] = dinv[d]*(sum_s dinv[s]*h[s] + dinv[d]*h[d]) ------
// wave per node, lane = feature (64)

template <bool RELU_BIAS>
__global__ __launch_bounds__(256) void k_prop(const float* __restrict__ hpre,
                                              const int* __restrict__ row_ptr,
                                              const int* __restrict__ ssorted,
                                              const float* __restrict__ dinv,
                                              const float* __restrict__ bias,
                                              float* __restrict__ out, int n) {
    int lane = threadIdx.x & 63, wid = threadIdx.x >> 6;
    int d = blockIdx.x * 4 + wid;
    if (d >= n) return;
    float dd = dinv[d];
    float acc = dd * hpre[(size_t)d * 64 + lane];  // self loop (inner dinv[d])
    int s0 = row_ptr[d], s1 = row_ptr[d + 1];
    for (int base = s0; base < s1; base += 64) {
        int j = base + lane;
        int sl = 0;
        float wl = 0.f;
        if (j < s1) { sl = ssorted[j]; wl = dinv[sl]; }
        int cnt = min(64, s1 - base);
        int i = 0;
        for (; i + 4 <= cnt; i += 4) {
            int a0 = __shfl(sl, i), a1 = __shfl(sl, i + 1);
            int a2 = __shfl(sl, i + 2), a3 = __shfl(sl, i + 3);
            float w0 = __shfl(wl, i), w1 = __shfl(wl, i + 1);
            float w2 = __shfl(wl, i + 2), w3 = __shfl(wl, i + 3);
            float v0 = hpre[(size_t)a0 * 64 + lane];
            float v1 = hpre[(size_t)a1 * 64 + lane];
            float v2 = hpre[(size_t)a2 * 64 + lane];
            float v3 = hpre[(size_t)a3 * 64 + lane];
            acc += w0 * v0; acc += w1 * v1; acc += w2 * v2; acc += w3 * v3;
        }
        for (; i < cnt; i++) {
            int a = __shfl(sl, i);
            float w = __shfl(wl, i);
            acc += w * hpre[(size_t)a * 64 + lane];
        }
    }
    float val = dd * acc;
    if (RELU_BIAS) val = fmaxf(val + bias[lane], 0.f);
    out[(size_t)d * 64 + lane] = val;
}

// ---------------- fused middle: z = h1@Wz+bz ; pred = z@Wc+bc ; hd = relu(z@Wd+bd) -------
// wave per node; lane = feature

__global__ __launch_bounds__(256) void k_mid(const float* __restrict__ h1,
                                             const float* __restrict__ Wz, const float* __restrict__ bz,
                                             const float* __restrict__ Wd, const float* __restrict__ bd,
                                             const float* __restrict__ Wc, const float* __restrict__ bc,
                                             float* __restrict__ hd_ws,
                                             float* __restrict__ z_out, float* __restrict__ pred_out,
                                             int n) {
    __shared__ float Wzs[64 * 33];  // [k][j] padded
    __shared__ float Wds[32 * 65];  // [j][f] padded
    __shared__ float Wcs[32 * 3];
    __shared__ float bzs[32], bds[64], bcs[3];
    int tid = threadIdx.x;
    for (int i = tid; i < 64 * 32; i += 256) { int k = i >> 5, j = i & 31; Wzs[k * 33 + j] = Wz[i]; }
    for (int i = tid; i < 32 * 64; i += 256) { int k = i >> 6, j = i & 63; Wds[k * 65 + j] = Wd[i]; }
    if (tid < 96) Wcs[tid] = Wc[tid];
    if (tid < 32) bzs[tid] = bz[tid];
    if (tid < 64) bds[tid] = bd[tid];
    if (tid < 3)  bcs[tid] = bc[tid];
    __syncthreads();
    int lane = tid & 63, wid = tid >> 6;
    int node = blockIdx.x * 4 + wid;
    if (node >= n) return;

    float h = h1[(size_t)node * 64 + lane];
    float zreg = 0.f;
    for (int j = 0; j < 32; j++) {
        float t = h * Wzs[lane * 33 + j];
        for (int m = 1; m < 64; m <<= 1) t += __shfl_xor(t, m);
        t += bzs[j];
        if (lane == j) zreg = t;
    }
    if (lane < 32) z_out[(size_t)node * 32 + lane] = zreg;
    float hdv = bds[lane];
    float pa = bcs[0], pb = bcs[1], pc = bcs[2];
    for (int j = 0; j < 32; j++) {
        float zj = __shfl(zreg, j);
        hdv += zj * Wds[j * 65 + lane];
        pa += zj * Wcs[j * 3 + 0];
        pb += zj * Wcs[j * 3 + 1];
        pc += zj * Wcs[j * 3 + 2];
    }
    hdv = fmaxf(hdv, 0.f);
    hd_ws[(size_t)node * 64 + lane] = hdv;
    if (lane == 0) {
        pred_out[(size_t)node * 3 + 0] = pa;
        pred_out[(size_t)node * 3 + 1] = pb;
        pred_out[(size_t)node * 3 + 2] = pc;
    }
}

// ---------------- GEMM5: x_recon[n,256] = p2[n,64] @ W_dec_gnn[64,256] + b (fp32) ---

__global__ __launch_bounds__(256) void k_gemm5(const float* __restrict__ A,
                                               const float* __restrict__ W,
                                               const float* __restrict__ bias,
                                               float* __restrict__ out, int n) {
    __shared__ f16 Wh[64 * 256];  // 32 KB
    __shared__ float As[4 * 64];
    __shared__ float bs[256];
    int tid = threadIdx.x;
    for (int i = tid * 4; i < 64 * 256; i += 1024) {
        float4 w = *(const float4*)&W[i];
        Wh[i + 0] = (f16)w.x;
        Wh[i + 1] = (f16)w.y;
        Wh[i + 2] = (f16)w.z;
        Wh[i + 3] = (f16)w.w;
    }
    bs[tid] = bias[tid];
    int row0 = blockIdx.x * 4;
    {
        int r = tid >> 6, k = tid & 63;
        int gr = row0 + r;
        As[tid] = (gr < n) ? A[(size_t)gr * 64 + k] : 0.f;
    }
    __syncthreads();
    int r = tid >> 6;          // wave id = row
    int cg = (tid & 63) * 4;   // col group
    float4 acc = {0.f, 0.f, 0.f, 0.f};
    const float* ap = &As[r * 64];
#pragma unroll 8
    for (int k = 0; k < 64; k++) {
        float a = ap[k];
        half4 w = *(const half4*)&Wh[k * 256 + cg];
        acc.x += a * (float)w.x;
        acc.y += a * (float)w.y;
        acc.z += a * (float)w.z;
        acc.w += a * (float)w.w;
    }
    int gr = row0 + r;
    if (gr < n) {
        float4 o;
        o.x = acc.x + bs[cg + 0];
        o.y = acc.y + bs[cg + 1];
        o.z = acc.z + bs[cg + 2];
        o.w = acc.w + bs[cg + 3];
        *(float4*)&out[(size_t)gr * 256 + cg] = o;
    }
}

// ---------------- launch ----------------

extern "C" void kernel_launch(void* const* d_in, const int* in_sizes, int n_in,
                              void* d_out, int out_size, void* d_ws, size_t ws_size,
                              hipStream_t stream) {
    const float* x    = (const float*)d_in[0];
    const int*   ei   = (const int*)d_in[1];
    const float* Wenc = (const float*)d_in[3];
    const float* benc = (const float*)d_in[4];
    const float* Wz   = (const float*)d_in[5];
    const float* bz   = (const float*)d_in[6];
    const float* Wd   = (const float*)d_in[7];
    const float* bd   = (const float*)d_in[8];
    const float* Wdec = (const float*)d_in[9];
    const float* bdec = (const float*)d_in[10];
    const float* Wc   = (const float*)d_in[11];
    const float* bc   = (const float*)d_in[12];

    int n = in_sizes[0] / 256;
    int E = in_sizes[1] / 2;
    const int* src = ei;
    const int* dst = ei + E;

    // workspace carve-out (~30 MB total)
    char* w = (char*)d_ws;
    size_t off = 0;
    auto alloc = [&](size_t bytes) {
        void* p = w + off;
        off = (off + bytes + 255) & ~(size_t)255;
        return p;
    };
    int*   cnt     = (int*)alloc(sizeof(int) * n);
    int*   row_ptr = (int*)alloc(sizeof(int) * (n + 1));
    int*   cursor  = (int*)alloc(sizeof(int) * n);
    int*   ssorted = (int*)alloc(sizeof(int) * E);
    float* dinv    = (float*)alloc(sizeof(float) * n);
    float* bufA    = (float*)alloc(sizeof(float) * (size_t)n * 64);  // h1pre -> hd
    float* bufB    = (float*)alloc(sizeof(float) * (size_t)n * 64);  // h1 -> p2
    (void)ws_size; (void)n_in; (void)out_size;

    float* out_xr = (float*)d_out;
    float* out_z  = out_xr + (size_t)n * 256;
    float* out_p  = out_z + (size_t)n * 32;

    // CSR build
    k_zero_int<<<dim3((n + 255) / 256), dim3(256), 0, stream>>>(cnt, n);
    k_count<<<dim3((E + 255) / 256), dim3(256), 0, stream>>>(dst, E, cnt);
    k_scan<<<dim3(1), dim3(1024), 0, stream>>>(cnt, n, E, row_ptr, cursor, dinv);
    k_fill<<<dim3((E + 255) / 256), dim3(256), 0, stream>>>(src, dst, E, cursor, ssorted);

    // encoder: bufA = x @ W_enc ; bufB = relu(P bufA + b_enc)
    k_gemm1<<<dim3((n + G1_R - 1) / G1_R), dim3(256), 0, stream>>>(x, Wenc, bufA, n);
    k_prop<true><<<dim3((n + 3) / 4), dim3(256), 0, stream>>>(bufA, row_ptr, ssorted, dinv, benc, bufB, n);

    // middle: z (out), pred (out), hd -> bufA
    k_mid<<<dim3((n + 3) / 4), dim3(256), 0, stream>>>(bufB, Wz, bz, Wd, bd, Wc, bc,
                                                       bufA, out_z, out_p, n);

    // decoder (reassociated): bufB = P bufA ; x_recon = bufB @ W_dec + b_dec
    k_prop<false><<<dim3((n + 3) / 4), dim3(256), 0, stream>>>(bufA, row_ptr, ssorted, dinv, benc, bufB, n);
    k_gemm5<<<dim3((n + 3) / 4), dim3(256), 0, stream>>>(bufB, Wdec, bdec, out_xr, n);
}

// Round 3
// 576.203 us; speedup vs baseline: 1.1669x; 1.1669x over previous
//
#include <hip/hip_runtime.h>
#include <hip/hip_bf16.h>
#include <stdint.h>

typedef _Float16 f16;
typedef _Float16 half4 __attribute__((ext_vector_type(4)));

// ---------------- CSR build ----------------

__global__ void k_zero_int(int* __restrict__ p, int n) {
    int i = blockIdx.x * blockDim.x + threadIdx.x;
    if (i < n) p[i] = 0;
}

__global__ void k_count(const int* __restrict__ dst, int E, int* __restrict__ cnt) {
    int e = blockIdx.x * blockDim.x + threadIdx.x;
    if (e < E) atomicAdd(&cnt[dst[e]], 1);
}

// single block, 1024 threads: exclusive scan of cnt -> row_ptr/cursor, dinv = rsqrt(deg+1)
__global__ void k_scan(const int* __restrict__ cnt, int n, int E,
                       int* __restrict__ row_ptr, int* __restrict__ cursor,
                       float* __restrict__ dinv) {
    const int T = 1024;
    int tid = threadIdx.x;
    int seg = (n + T - 1) / T;
    int lo = tid * seg;
    int hi = min(lo + seg, n);
    int s = 0;
    for (int i = lo; i < hi; i++) s += cnt[i];

    __shared__ int wsum[16];
    int lane = tid & 63, wid = tid >> 6;
    int v = s;
    for (int off = 1; off < 64; off <<= 1) {
        int u = __shfl_up(v, off);
        if (lane >= off) v += u;
    }
    if (lane == 63) wsum[wid] = v;
    __syncthreads();
    if (wid == 0) {
        int wv = (lane < 16) ? wsum[lane] : 0;
        for (int off = 1; off < 16; off <<= 1) {
            int u = __shfl_up(wv, off);
            if (lane >= off) wv += u;
        }
        if (lane < 16) wsum[lane] = wv;
    }
    __syncthreads();
    int base = ((wid > 0) ? wsum[wid - 1] : 0) + (v - s);  // exclusive prefix of this thread
    int run = base;
    for (int i = lo; i < hi; i++) {
        row_ptr[i] = run;
        cursor[i] = run;
        int c = cnt[i];
        dinv[i] = rsqrtf((float)(c + 1));  // +1 self loop, deg always > 0
        run += c;
    }
    if (tid == 0) row_ptr[n] = E;
}

__global__ void k_fill(const int* __restrict__ src, const int* __restrict__ dst, int E,
                       int* __restrict__ cursor, int* __restrict__ ssorted) {
    int e = blockIdx.x * blockDim.x + threadIdx.x;
    if (e < E) {
        int p = atomicAdd(&cursor[dst[e]], 1);
        ssorted[p] = src[e];
    }
}

// ---------------- GEMM1: h1_pre[n,64] = x[n,256] @ W_enc_gnn[256,64] (fp32) ---------

#define G1_R 16
__global__ __launch_bounds__(256) void k_gemm1(const float* __restrict__ x,
                                               const float* __restrict__ W,
                                               float* __restrict__ out, int n) {
    __shared__ f16 Wh[256 * 64];     // 32 KB
    __shared__ float As[G1_R * 257]; // padded rows, 16.4 KB
    int tid = threadIdx.x;
    for (int i = tid * 4; i < 256 * 64; i += 1024) {
        float4 w = *(const float4*)&W[i];
        Wh[i + 0] = (f16)w.x;
        Wh[i + 1] = (f16)w.y;
        Wh[i + 2] = (f16)w.z;
        Wh[i + 3] = (f16)w.w;
    }
    int row0 = blockIdx.x * G1_R;
    for (int i4 = tid; i4 < G1_R * 64; i4 += 256) {  // 64 float4 per row
        int r = i4 >> 6, k4 = (i4 & 63) * 4;
        int gr = row0 + r;
        float4 xx = {0.f, 0.f, 0.f, 0.f};
        if (gr < n) xx = *(const float4*)&x[(size_t)gr * 256 + k4];
        As[r * 257 + k4 + 0] = xx.x;
        As[r * 257 + k4 + 1] = xx.y;
        As[r * 257 + k4 + 2] = xx.z;
        As[r * 257 + k4 + 3] = xx.w;
    }
    __syncthreads();
    int r = tid >> 4;          // 0..15
    int cg = (tid & 15) * 4;   // col group
    float4 acc = {0.f, 0.f, 0.f, 0.f};
    const float* ap = &As[r * 257];
#pragma unroll 4
    for (int k = 0; k < 256; k++) {
        float a = ap[k];
        half4 w = *(const half4*)&Wh[k * 64 + cg];
        acc.x += a * (float)w.x;
        acc.y += a * (float)w.y;
        acc.z += a * (float)w.z;
        acc.w += a * (float)w.w;
    }
    int gr = row0 + r;
    if (gr < n) *(float4*)&out[(size_t)gr * 64 + cg] = acc;
}

// ---------------- propagation: out[d] = dinv[d]*(sum_s dinv[s]*h[s] + dinv[d]*h[d]) ------
// wave per node, lane = feature (64)

template <bool RELU_BIAS>
__global__ __launch_bounds__(256) void k_prop(const float* __restrict__ hpre,
                                              const int* __restrict__ row_ptr,
                                              const int* __restrict__ ssorted,
                                              const float* __restrict__ dinv,
                                              const float* __restrict__ bias,
                                              float* __restrict__ out, int n) {
    int lane = threadIdx.x & 63, wid = threadIdx.x >> 6;
    int d = blockIdx.x * 4 + wid;
    if (d >= n) return;
    float dd = dinv[d];
    float acc = dd * hpre[(size_t)d * 64 + lane];  // self loop (inner dinv[d])
    int s0 = row_ptr[d], s1 = row_ptr[d + 1];
    for (int base = s0; base < s1; base += 64) {
        int j = base + lane;
        int sl = 0;
        float wl = 0.f;
        if (j < s1) { sl = ssorted[j]; wl = dinv[sl]; }
        int cnt = min(64, s1 - base);
        int i = 0;
        for (; i + 4 <= cnt; i += 4) {
            int a0 = __shfl(sl, i), a1 = __shfl(sl, i + 1);
            int a2 = __shfl(sl, i + 2), a3 = __shfl(sl, i + 3);
            float w0 = __shfl(wl, i), w1 = __shfl(wl, i + 1);
            float w2 = __shfl(wl, i + 2), w3 = __shfl(wl, i + 3);
            float v0 = hpre[(size_t)a0 * 64 + lane];
            float v1 = hpre[(size_t)a1 * 64 + lane];
            float v2 = hpre[(size_t)a2 * 64 + lane];
            float v3 = hpre[(size_t)a3 * 64 + lane];
            acc += w0 * v0; acc += w1 * v1; acc += w2 * v2; acc += w3 * v3;
        }
        for (; i < cnt; i++) {
            int a = __shfl(sl, i);
            float w = __shfl(wl, i);
            acc += w * hpre[(size_t)a * 64 + lane];
        }
    }
    float val = dd * acc;
    if (RELU_BIAS) val = fmaxf(val + bias[lane], 0.f);
    out[(size_t)d * 64 + lane] = val;
}

// ---------------- fused middle (tile-GEMM rewrite): 64 nodes per block ----------------
// z = h1@Wz+bz ; pred = z@Wc+bc ; hd = relu(z@Wd+bd). No shuffles: LDS tiles only.

#define MB 64
__global__ __launch_bounds__(256) void k_mid(const float* __restrict__ h1,
                                             const float* __restrict__ Wz, const float* __restrict__ bz,
                                             const float* __restrict__ Wd, const float* __restrict__ bd,
                                             const float* __restrict__ Wc, const float* __restrict__ bc,
                                             float* __restrict__ hd_ws,
                                             float* __restrict__ z_out, float* __restrict__ pred_out,
                                             int n) {
    __shared__ float Hs[MB * 68];    // h1 tile, padded stride 68 (16B-aligned rows)
    __shared__ float Zs[MB * 36];    // z tile, padded stride 36
    __shared__ float Wzs[64 * 32];   // [k][j]
    __shared__ float Wds[32 * 64];   // [k][f]
    __shared__ float Wcs[32 * 4];    // [k][c], padded
    __shared__ float bzs[32], bds[64], bcs[4];
    int tid = threadIdx.x;
    for (int i = tid; i < 64 * 32; i += 256) Wzs[i] = Wz[i];
    for (int i = tid; i < 32 * 64; i += 256) Wds[i] = Wd[i];
    if (tid < 96) Wcs[(tid / 3) * 4 + (tid % 3)] = Wc[tid];
    if (tid < 32) bzs[tid] = bz[tid];
    if (tid < 64) bds[tid] = bd[tid];
    if (tid < 3)  bcs[tid] = bc[tid];
    int row0 = blockIdx.x * MB;
    for (int i4 = tid; i4 < MB * 16; i4 += 256) {
        int r = i4 >> 4, c4 = (i4 & 15) * 4;
        float4 v = {0.f, 0.f, 0.f, 0.f};
        if (row0 + r < n) v = *(const float4*)&h1[(size_t)(row0 + r) * 64 + c4];
        *(float4*)&Hs[r * 68 + c4] = v;
    }
    __syncthreads();

    // phase A: z[node][j] = sum_k Hs[node][k] * Wz[k][j] + bz[j]
    {
        int j = tid & 31, g = tid >> 5;  // 8 node-groups
        float acc[8] = {0.f, 0.f, 0.f, 0.f, 0.f, 0.f, 0.f, 0.f};
        for (int k = 0; k < 64; k++) {
            float wv = Wzs[k * 32 + j];
#pragma unroll
            for (int r = 0; r < 8; r++) acc[r] += Hs[(g + 8 * r) * 68 + k] * wv;
        }
        float bj = bzs[j];
#pragma unroll
        for (int r = 0; r < 8; r++) {
            int node = g + 8 * r;
            float zv = acc[r] + bj;
            Zs[node * 36 + j] = zv;
            if (row0 + node < n) z_out[(size_t)(row0 + node) * 32 + j] = zv;
        }
    }
    __syncthreads();

    // phase B: hd[node][f] = relu(sum_k Zs[node][k] * Wd[k][f] + bd[f])
    {
        int f = tid & 63, g = tid >> 6;  // 4 node-groups
        float acc[16];
#pragma unroll
        for (int r = 0; r < 16; r++) acc[r] = bds[f];
        for (int k = 0; k < 32; k++) {
            float wv = Wds[k * 64 + f];
#pragma unroll
            for (int r = 0; r < 16; r++) acc[r] += Zs[(g + 4 * r) * 36 + k] * wv;
        }
#pragma unroll
        for (int r = 0; r < 16; r++) {
            int node = g + 4 * r;
            if (row0 + node < n) hd_ws[(size_t)(row0 + node) * 64 + f] = fmaxf(acc[r], 0.f);
        }
    }

    // pred: wave 0, one node per lane
    if (tid < 64) {
        int node = tid;
        float pa = bcs[0], pb = bcs[1], pc = bcs[2];
        for (int k = 0; k < 32; k++) {
            float zv = Zs[node * 36 + k];
            pa += zv * Wcs[k * 4 + 0];
            pb += zv * Wcs[k * 4 + 1];
            pc += zv * Wcs[k * 4 + 2];
        }
        if (row0 + node < n) {
            pred_out[(size_t)(row0 + node) * 3 + 0] = pa;
            pred_out[(size_t)(row0 + node) * 3 + 1] = pb;
            pred_out[(size_t)(row0 + node) * 3 + 2] = pc;
        }
    }
}

// ---------------- GEMM5: x_recon[n,256] = p2[n,64] @ W_dec_gnn[64,256] + b (fp32) ---

__global__ __launch_bounds__(256) void k_gemm5(const float* __restrict__ A,
                                               const float* __restrict__ W,
                                               const float* __restrict__ bias,
                                               float* __restrict__ out, int n) {
    __shared__ f16 Wh[64 * 256];  // 32 KB
    __shared__ float As[4 * 64];
    __shared__ float bs[256];
    int tid = threadIdx.x;
    for (int i = tid * 4; i < 64 * 256; i += 1024) {
        float4 w = *(const float4*)&W[i];
        Wh[i + 0] = (f16)w.x;
        Wh[i + 1] = (f16)w.y;
        Wh[i + 2] = (f16)w.z;
        Wh[i + 3] = (f16)w.w;
    }
    bs[tid] = bias[tid];
    int row0 = blockIdx.x * 4;
    {
        int r = tid >> 6, k = tid & 63;
        int gr = row0 + r;
        As[tid] = (gr < n) ? A[(size_t)gr * 64 + k] : 0.f;
    }
    __syncthreads();
    int r = tid >> 6;          // wave id = row
    int cg = (tid & 63) * 4;   // col group
    float4 acc = {0.f, 0.f, 0.f, 0.f};
    const float* ap = &As[r * 64];
#pragma unroll 8
    for (int k = 0; k < 64; k++) {
        float a = ap[k];
        half4 w = *(const half4*)&Wh[k * 256 + cg];
        acc.x += a * (float)w.x;
        acc.y += a * (float)w.y;
        acc.z += a * (float)w.z;
        acc.w += a * (float)w.w;
    }
    int gr = row0 + r;
    if (gr < n) {
        float4 o;
        o.x = acc.x + bs[cg + 0];
        o.y = acc.y + bs[cg + 1];
        o.z = acc.z + bs[cg + 2];
        o.w = acc.w + bs[cg + 3];
        *(float4*)&out[(size_t)gr * 256 + cg] = o;
    }
}

// ---------------- launch ----------------

extern "C" void kernel_launch(void* const* d_in, const int* in_sizes, int n_in,
                              void* d_out, int out_size, void* d_ws, size_t ws_size,
                              hipStream_t stream) {
    const float* x    = (const float*)d_in[0];
    const int*   ei   = (const int*)d_in[1];
    const float* Wenc = (const float*)d_in[3];
    const float* benc = (const float*)d_in[4];
    const float* Wz   = (const float*)d_in[5];
    const float* bz   = (const float*)d_in[6];
    const float* Wd   = (const float*)d_in[7];
    const float* bd   = (const float*)d_in[8];
    const float* Wdec = (const float*)d_in[9];
    const float* bdec = (const float*)d_in[10];
    const float* Wc   = (const float*)d_in[11];
    const float* bc   = (const float*)d_in[12];

    int n = in_sizes[0] / 256;
    int E = in_sizes[1] / 2;
    const int* src = ei;
    const int* dst = ei + E;

    // workspace carve-out (~30 MB total)
    char* w = (char*)d_ws;
    size_t off = 0;
    auto alloc = [&](size_t bytes) {
        void* p = w + off;
        off = (off + bytes + 255) & ~(size_t)255;
        return p;
    };
    int*   cnt     = (int*)alloc(sizeof(int) * n);
    int*   row_ptr = (int*)alloc(sizeof(int) * (n + 1));
    int*   cursor  = (int*)alloc(sizeof(int) * n);
    int*   ssorted = (int*)alloc(sizeof(int) * E);
    float* dinv    = (float*)alloc(sizeof(float) * n);
    float* bufA    = (float*)alloc(sizeof(float) * (size_t)n * 64);  // h1pre -> hd
    float* bufB    = (float*)alloc(sizeof(float) * (size_t)n * 64);  // h1 -> p2
    (void)ws_size; (void)n_in; (void)out_size;

    float* out_xr = (float*)d_out;
    float* out_z  = out_xr + (size_t)n * 256;
    float* out_p  = out_z + (size_t)n * 32;

    // CSR build
    k_zero_int<<<dim3((n + 255) / 256), dim3(256), 0, stream>>>(cnt, n);
    k_count<<<dim3((E + 255) / 256), dim3(256), 0, stream>>>(dst, E, cnt);
    k_scan<<<dim3(1), dim3(1024), 0, stream>>>(cnt, n, E, row_ptr, cursor, dinv);
    k_fill<<<dim3((E + 255) / 256), dim3(256), 0, stream>>>(src, dst, E, cursor, ssorted);

    // encoder: bufA = x @ W_enc ; bufB = relu(P bufA + b_enc)
    k_gemm1<<<dim3((n + G1_R - 1) / G1_R), dim3(256), 0, stream>>>(x, Wenc, bufA, n);
    k_prop<true><<<dim3((n + 3) / 4), dim3(256), 0, stream>>>(bufA, row_ptr, ssorted, dinv, benc, bufB, n);

    // middle: z (out), pred (out), hd -> bufA
    k_mid<<<dim3((n + MB - 1) / MB), dim3(256), 0, stream>>>(bufB, Wz, bz, Wd, bd, Wc, bc,
                                                             bufA, out_z, out_p, n);

    // decoder (reassociated): bufB = P bufA ; x_recon = bufB @ W_dec + b_dec
    k_prop<false><<<dim3((n + 3) / 4), dim3(256), 0, stream>>>(bufA, row_ptr, ssorted, dinv, benc, bufB, n);
    k_gemm5<<<dim3((n + 3) / 4), dim3(256), 0, stream>>>(bufB, Wdec, bdec, out_xr, n);
}

// Round 4
// 448.808 us; speedup vs baseline: 1.4981x; 1.2839x over previous
//
#include <hip/hip_runtime.h>
#include <hip/hip_bf16.h>
#include <stdint.h>

typedef _Float16 f16;
typedef _Float16 half4 __attribute__((ext_vector_type(4)));

// ---------------- CSR build ----------------

__global__ void k_zero_int(int* __restrict__ p, int n) {
    int i = blockIdx.x * blockDim.x + threadIdx.x;
    if (i < n) p[i] = 0;
}

__global__ void k_count(const int* __restrict__ dst, int E, int* __restrict__ cnt) {
    int e = blockIdx.x * blockDim.x + threadIdx.x;
    if (e < E) atomicAdd(&cnt[dst[e]], 1);
}

// phase 1: per-block (256-wide) reduction of cnt -> bsum[block]
__global__ __launch_bounds__(256) void k_scan1(const int* __restrict__ cnt, int n,
                                               int* __restrict__ bsum) {
    __shared__ int red[256];
    int tid = threadIdx.x;
    int i = blockIdx.x * 256 + tid;
    red[tid] = (i < n) ? cnt[i] : 0;
    __syncthreads();
    for (int o = 128; o > 0; o >>= 1) {
        if (tid < o) red[tid] += red[tid + o];
        __syncthreads();
    }
    if (tid == 0) bsum[blockIdx.x] = red[0];
}

// phase 2: single block exclusive scan of bsum (nb <= 256)
__global__ __launch_bounds__(256) void k_scan2(const int* __restrict__ bsum, int nb,
                                               int* __restrict__ boff) {
    __shared__ int s[256];
    int tid = threadIdx.x;
    int v = (tid < nb) ? bsum[tid] : 0;
    s[tid] = v;
    __syncthreads();
    for (int o = 1; o < 256; o <<= 1) {
        int t = (tid >= o) ? s[tid - o] : 0;
        __syncthreads();
        s[tid] += t;
        __syncthreads();
    }
    if (tid < nb) boff[tid] = s[tid] - v;  // exclusive
}

// phase 3: in-block exclusive scan + block offset -> row_ptr/cursor, dinv
__global__ __launch_bounds__(256) void k_scan3(const int* __restrict__ cnt, int n, int E,
                                               const int* __restrict__ boff,
                                               int* __restrict__ row_ptr, int* __restrict__ cursor,
                                               float* __restrict__ dinv) {
    __shared__ int s[256];
    int tid = threadIdx.x;
    int i = blockIdx.x * 256 + tid;
    int c = (i < n) ? cnt[i] : 0;
    s[tid] = c;
    __syncthreads();
    for (int o = 1; o < 256; o <<= 1) {
        int t = (tid >= o) ? s[tid - o] : 0;
        __syncthreads();
        s[tid] += t;
        __syncthreads();
    }
    if (i < n) {
        int excl = boff[blockIdx.x] + s[tid] - c;
        row_ptr[i] = excl;
        cursor[i] = excl;
        dinv[i] = rsqrtf((float)(c + 1));  // +1 self loop
    }
    if (blockIdx.x == 0 && tid == 0) row_ptr[n] = E;
}

__global__ void k_fill(const int* __restrict__ src, const int* __restrict__ dst, int E,
                       int* __restrict__ cursor, int* __restrict__ ssorted) {
    int e = blockIdx.x * blockDim.x + threadIdx.x;
    if (e < E) {
        int p = atomicAdd(&cursor[dst[e]], 1);
        ssorted[p] = src[e];
    }
}

// ---------------- GEMM1: h1_pre[n,64] = x[n,256] @ W_enc_gnn[256,64] (fp32) ---------

#define G1_R 16
__global__ __launch_bounds__(256) void k_gemm1(const float* __restrict__ x,
                                               const float* __restrict__ W,
                                               float* __restrict__ out, int n) {
    __shared__ f16 Wh[256 * 64];     // 32 KB
    __shared__ float As[G1_R * 257]; // padded rows, 16.4 KB
    int tid = threadIdx.x;
    for (int i = tid * 4; i < 256 * 64; i += 1024) {
        float4 w = *(const float4*)&W[i];
        Wh[i + 0] = (f16)w.x;
        Wh[i + 1] = (f16)w.y;
        Wh[i + 2] = (f16)w.z;
        Wh[i + 3] = (f16)w.w;
    }
    int row0 = blockIdx.x * G1_R;
    for (int i4 = tid; i4 < G1_R * 64; i4 += 256) {  // 64 float4 per row
        int r = i4 >> 6, k4 = (i4 & 63) * 4;
        int gr = row0 + r;
        float4 xx = {0.f, 0.f, 0.f, 0.f};
        if (gr < n) xx = *(const float4*)&x[(size_t)gr * 256 + k4];
        As[r * 257 + k4 + 0] = xx.x;
        As[r * 257 + k4 + 1] = xx.y;
        As[r * 257 + k4 + 2] = xx.z;
        As[r * 257 + k4 + 3] = xx.w;
    }
    __syncthreads();
    int r = tid >> 4;          // 0..15
    int cg = (tid & 15) * 4;   // col group
    float4 acc = {0.f, 0.f, 0.f, 0.f};
    const float* ap = &As[r * 257];
#pragma unroll 4
    for (int k = 0; k < 256; k++) {
        float a = ap[k];
        half4 w = *(const half4*)&Wh[k * 64 + cg];
        acc.x += a * (float)w.x;
        acc.y += a * (float)w.y;
        acc.z += a * (float)w.z;
        acc.w += a * (float)w.w;
    }
    int gr = row0 + r;
    if (gr < n) *(float4*)&out[(size_t)gr * 64 + cg] = acc;
}

// ---------------- propagation: out[d] = dinv[d]*(sum_s dinv[s]*h[s] + dinv[d]*h[d]) ------
// wave per node, lane = feature (64)

template <bool RELU_BIAS>
__global__ __launch_bounds__(256) void k_prop(const float* __restrict__ hpre,
                                              const int* __restrict__ row_ptr,
                                              const int* __restrict__ ssorted,
                                              const float* __restrict__ dinv,
                                              const float* __restrict__ bias,
                                              float* __restrict__ out, int n) {
    int lane = threadIdx.x & 63, wid = threadIdx.x >> 6;
    int d = blockIdx.x * 4 + wid;
    if (d >= n) return;
    float dd = dinv[d];
    float acc = dd * hpre[(size_t)d * 64 + lane];  // self loop (inner dinv[d])
    int s0 = row_ptr[d], s1 = row_ptr[d + 1];
    for (int base = s0; base < s1; base += 64) {
        int j = base + lane;
        int sl = 0;
        float wl = 0.f;
        if (j < s1) { sl = ssorted[j]; wl = dinv[sl]; }
        int cnt = min(64, s1 - base);
        int i = 0;
        for (; i + 4 <= cnt; i += 4) {
            int a0 = __shfl(sl, i), a1 = __shfl(sl, i + 1);
            int a2 = __shfl(sl, i + 2), a3 = __shfl(sl, i + 3);
            float w0 = __shfl(wl, i), w1 = __shfl(wl, i + 1);
            float w2 = __shfl(wl, i + 2), w3 = __shfl(wl, i + 3);
            float v0 = hpre[(size_t)a0 * 64 + lane];
            float v1 = hpre[(size_t)a1 * 64 + lane];
            float v2 = hpre[(size_t)a2 * 64 + lane];
            float v3 = hpre[(size_t)a3 * 64 + lane];
            acc += w0 * v0; acc += w1 * v1; acc += w2 * v2; acc += w3 * v3;
        }
        for (; i < cnt; i++) {
            int a = __shfl(sl, i);
            float w = __shfl(wl, i);
            acc += w * hpre[(size_t)a * 64 + lane];
        }
    }
    float val = dd * acc;
    if (RELU_BIAS) val = fmaxf(val + bias[lane], 0.f);
    out[(size_t)d * 64 + lane] = val;
}

// ---------------- fused middle (tile-GEMM): 64 nodes per block ----------------
// z = h1@Wz+bz ; pred = z@Wc+bc ; hd = relu(z@Wd+bd). No shuffles: LDS tiles only.

#define MB 64
__global__ __launch_bounds__(256) void k_mid(const float* __restrict__ h1,
                                             const float* __restrict__ Wz, const float* __restrict__ bz,
                                             const float* __restrict__ Wd, const float* __restrict__ bd,
                                             const float* __restrict__ Wc, const float* __restrict__ bc,
                                             float* __restrict__ hd_ws,
                                             float* __restrict__ z_out, float* __restrict__ pred_out,
                                             int n) {
    __shared__ float Hs[MB * 68];    // h1 tile, padded stride 68 (16B-aligned rows)
    __shared__ float Zs[MB * 36];    // z tile, padded stride 36
    __shared__ float Wzs[64 * 32];   // [k][j]
    __shared__ float Wds[32 * 64];   // [k][f]
    __shared__ float Wcs[32 * 4];    // [k][c], padded
    __shared__ float bzs[32], bds[64], bcs[4];
    int tid = threadIdx.x;
    for (int i = tid; i < 64 * 32; i += 256) Wzs[i] = Wz[i];
    for (int i = tid; i < 32 * 64; i += 256) Wds[i] = Wd[i];
    if (tid < 96) Wcs[(tid / 3) * 4 + (tid % 3)] = Wc[tid];
    if (tid < 32) bzs[tid] = bz[tid];
    if (tid < 64) bds[tid] = bd[tid];
    if (tid < 3)  bcs[tid] = bc[tid];
    int row0 = blockIdx.x * MB;
    for (int i4 = tid; i4 < MB * 16; i4 += 256) {
        int r = i4 >> 4, c4 = (i4 & 15) * 4;
        float4 v = {0.f, 0.f, 0.f, 0.f};
        if (row0 + r < n) v = *(const float4*)&h1[(size_t)(row0 + r) * 64 + c4];
        *(float4*)&Hs[r * 68 + c4] = v;
    }
    __syncthreads();

    // phase A: z[node][j] = sum_k Hs[node][k] * Wz[k][j] + bz[j]
    {
        int j = tid & 31, g = tid >> 5;  // 8 node-groups
        float acc[8] = {0.f, 0.f, 0.f, 0.f, 0.f, 0.f, 0.f, 0.f};
        for (int k = 0; k < 64; k++) {
            float wv = Wzs[k * 32 + j];
#pragma unroll
            for (int r = 0; r < 8; r++) acc[r] += Hs[(g + 8 * r) * 68 + k] * wv;
        }
        float bj = bzs[j];
#pragma unroll
        for (int r = 0; r < 8; r++) {
            int node = g + 8 * r;
            float zv = acc[r] + bj;
            Zs[node * 36 + j] = zv;
            if (row0 + node < n) z_out[(size_t)(row0 + node) * 32 + j] = zv;
        }
    }
    __syncthreads();

    // phase B: hd[node][f] = relu(sum_k Zs[node][k] * Wd[k][f] + bd[f])
    {
        int f = tid & 63, g = tid >> 6;  // 4 node-groups
        float acc[16];
#pragma unroll
        for (int r = 0; r < 16; r++) acc[r] = bds[f];
        for (int k = 0; k < 32; k++) {
            float wv = Wds[k * 64 + f];
#pragma unroll
            for (int r = 0; r < 16; r++) acc[r] += Zs[(g + 4 * r) * 36 + k] * wv;
        }
#pragma unroll
        for (int r = 0; r < 16; r++) {
            int node = g + 4 * r;
            if (row0 + node < n) hd_ws[(size_t)(row0 + node) * 64 + f] = fmaxf(acc[r], 0.f);
        }
    }

    // pred: wave 0, one node per lane
    if (tid < 64) {
        int node = tid;
        float pa = bcs[0], pb = bcs[1], pc = bcs[2];
        for (int k = 0; k < 32; k++) {
            float zv = Zs[node * 36 + k];
            pa += zv * Wcs[k * 4 + 0];
            pb += zv * Wcs[k * 4 + 1];
            pc += zv * Wcs[k * 4 + 2];
        }
        if (row0 + node < n) {
            pred_out[(size_t)(row0 + node) * 3 + 0] = pa;
            pred_out[(size_t)(row0 + node) * 3 + 1] = pb;
            pred_out[(size_t)(row0 + node) * 3 + 2] = pc;
        }
    }
}

// ---------------- GEMM5: x_recon[n,256] = p2[n,64] @ W_dec_gnn[64,256] + b (fp32) ---

__global__ __launch_bounds__(256) void k_gemm5(const float* __restrict__ A,
                                               const float* __restrict__ W,
                                               const float* __restrict__ bias,
                                               float* __restrict__ out, int n) {
    __shared__ f16 Wh[64 * 256];  // 32 KB
    __shared__ float As[4 * 64];
    __shared__ float bs[256];
    int tid = threadIdx.x;
    for (int i = tid * 4; i < 64 * 256; i += 1024) {
        float4 w = *(const float4*)&W[i];
        Wh[i + 0] = (f16)w.x;
        Wh[i + 1] = (f16)w.y;
        Wh[i + 2] = (f16)w.z;
        Wh[i + 3] = (f16)w.w;
    }
    bs[tid] = bias[tid];
    int row0 = blockIdx.x * 4;
    {
        int r = tid >> 6, k = tid & 63;
        int gr = row0 + r;
        As[tid] = (gr < n) ? A[(size_t)gr * 64 + k] : 0.f;
    }
    __syncthreads();
    int r = tid >> 6;          // wave id = row
    int cg = (tid & 63) * 4;   // col group
    float4 acc = {0.f, 0.f, 0.f, 0.f};
    const float* ap = &As[r * 64];
#pragma unroll 8
    for (int k = 0; k < 64; k++) {
        float a = ap[k];
        half4 w = *(const half4*)&Wh[k * 256 + cg];
        acc.x += a * (float)w.x;
        acc.y += a * (float)w.y;
        acc.z += a * (float)w.z;
        acc.w += a * (float)w.w;
    }
    int gr = row0 + r;
    if (gr < n) {
        float4 o;
        o.x = acc.x + bs[cg + 0];
        o.y = acc.y + bs[cg + 1];
        o.z = acc.z + bs[cg + 2];
        o.w = acc.w + bs[cg + 3];
        *(float4*)&out[(size_t)gr * 256 + cg] = o;
    }
}

// ---------------- launch ----------------

extern "C" void kernel_launch(void* const* d_in, const int* in_sizes, int n_in,
                              void* d_out, int out_size, void* d_ws, size_t ws_size,
                              hipStream_t stream) {
    const float* x    = (const float*)d_in[0];
    const int*   ei   = (const int*)d_in[1];
    const float* Wenc = (const float*)d_in[3];
    const float* benc = (const float*)d_in[4];
    const float* Wz   = (const float*)d_in[5];
    const float* bz   = (const float*)d_in[6];
    const float* Wd   = (const float*)d_in[7];
    const float* bd   = (const float*)d_in[8];
    const float* Wdec = (const float*)d_in[9];
    const float* bdec = (const float*)d_in[10];
    const float* Wc   = (const float*)d_in[11];
    const float* bc   = (const float*)d_in[12];

    int n = in_sizes[0] / 256;
    int E = in_sizes[1] / 2;
    const int* src = ei;
    const int* dst = ei + E;

    int nb = (n + 255) / 256;  // scan blocks (196 for n=50000)

    // workspace carve-out (~30 MB total)
    char* w = (char*)d_ws;
    size_t off = 0;
    auto alloc = [&](size_t bytes) {
        void* p = w + off;
        off = (off + bytes + 255) & ~(size_t)255;
        return p;
    };
    int*   cnt     = (int*)alloc(sizeof(int) * n);
    int*   row_ptr = (int*)alloc(sizeof(int) * (n + 1));
    int*   cursor  = (int*)alloc(sizeof(int) * n);
    int*   ssorted = (int*)alloc(sizeof(int) * E);
    float* dinv    = (float*)alloc(sizeof(float) * n);
    int*   bsum    = (int*)alloc(sizeof(int) * nb);
    int*   boff    = (int*)alloc(sizeof(int) * nb);
    float* bufA    = (float*)alloc(sizeof(float) * (size_t)n * 64);  // h1pre -> hd
    float* bufB    = (float*)alloc(sizeof(float) * (size_t)n * 64);  // h1 -> p2
    (void)ws_size; (void)n_in; (void)out_size;

    float* out_xr = (float*)d_out;
    float* out_z  = out_xr + (size_t)n * 256;
    float* out_p  = out_z + (size_t)n * 32;

    // CSR build (hierarchical scan)
    k_zero_int<<<dim3(nb), dim3(256), 0, stream>>>(cnt, n);
    k_count<<<dim3((E + 255) / 256), dim3(256), 0, stream>>>(dst, E, cnt);
    k_scan1<<<dim3(nb), dim3(256), 0, stream>>>(cnt, n, bsum);
    k_scan2<<<dim3(1), dim3(256), 0, stream>>>(bsum, nb, boff);
    k_scan3<<<dim3(nb), dim3(256), 0, stream>>>(cnt, n, E, boff, row_ptr, cursor, dinv);
    k_fill<<<dim3((E + 255) / 256), dim3(256), 0, stream>>>(src, dst, E, cursor, ssorted);

    // encoder: bufA = x @ W_enc ; bufB = relu(P bufA + b_enc)
    k_gemm1<<<dim3((n + G1_R - 1) / G1_R), dim3(256), 0, stream>>>(x, Wenc, bufA, n);
    k_prop<true><<<dim3((n + 3) / 4), dim3(256), 0, stream>>>(bufA, row_ptr, ssorted, dinv, benc, bufB, n);

    // middle: z (out), pred (out), hd -> bufA
    k_mid<<<dim3((n + MB - 1) / MB), dim3(256), 0, stream>>>(bufB, Wz, bz, Wd, bd, Wc, bc,
                                                             bufA, out_z, out_p, n);

    // decoder (reassociated): bufB = P bufA ; x_recon = bufB @ W_dec + b_dec
    k_prop<false><<<dim3((n + 3) / 4), dim3(256), 0, stream>>>(bufA, row_ptr, ssorted, dinv, benc, bufB, n);
    k_gemm5<<<dim3((n + 3) / 4), dim3(256), 0, stream>>>(bufB, Wdec, bdec, out_xr, n);
}

// Round 5
// 405.969 us; speedup vs baseline: 1.6562x; 1.1055x over previous
//
#include <hip/hip_runtime.h>
#include <hip/hip_bf16.h>
#include <stdint.h>

typedef _Float16 f16;
typedef _Float16 half4 __attribute__((ext_vector_type(4)));

// ---------------- CSR build ----------------

__global__ void k_zero_int(int* __restrict__ p, int n) {
    int i = blockIdx.x * blockDim.x + threadIdx.x;
    if (i < n) p[i] = 0;
}

__global__ void k_count(const int* __restrict__ dst, int E, int* __restrict__ cnt) {
    int e = blockIdx.x * blockDim.x + threadIdx.x;
    if (e < E) atomicAdd(&cnt[dst[e]], 1);
}

// phase 1: per-block (256-wide) reduction of cnt -> bsum[block]
__global__ __launch_bounds__(256) void k_scan1(const int* __restrict__ cnt, int n,
                                               int* __restrict__ bsum) {
    __shared__ int red[256];
    int tid = threadIdx.x;
    int i = blockIdx.x * 256 + tid;
    red[tid] = (i < n) ? cnt[i] : 0;
    __syncthreads();
    for (int o = 128; o > 0; o >>= 1) {
        if (tid < o) red[tid] += red[tid + o];
        __syncthreads();
    }
    if (tid == 0) bsum[blockIdx.x] = red[0];
}

// phase 2: single block exclusive scan of bsum (nb <= 256)
__global__ __launch_bounds__(256) void k_scan2(const int* __restrict__ bsum, int nb,
                                               int* __restrict__ boff) {
    __shared__ int s[256];
    int tid = threadIdx.x;
    int v = (tid < nb) ? bsum[tid] : 0;
    s[tid] = v;
    __syncthreads();
    for (int o = 1; o < 256; o <<= 1) {
        int t = (tid >= o) ? s[tid - o] : 0;
        __syncthreads();
        s[tid] += t;
        __syncthreads();
    }
    if (tid < nb) boff[tid] = s[tid] - v;  // exclusive
}

// phase 3: in-block exclusive scan + block offset -> row_ptr/cursor, dinv
__global__ __launch_bounds__(256) void k_scan3(const int* __restrict__ cnt, int n, int E,
                                               const int* __restrict__ boff,
                                               int* __restrict__ row_ptr, int* __restrict__ cursor,
                                               float* __restrict__ dinv) {
    __shared__ int s[256];
    int tid = threadIdx.x;
    int i = blockIdx.x * 256 + tid;
    int c = (i < n) ? cnt[i] : 0;
    s[tid] = c;
    __syncthreads();
    for (int o = 1; o < 256; o <<= 1) {
        int t = (tid >= o) ? s[tid - o] : 0;
        __syncthreads();
        s[tid] += t;
        __syncthreads();
    }
    if (i < n) {
        int excl = boff[blockIdx.x] + s[tid] - c;
        row_ptr[i] = excl;
        cursor[i] = excl;
        dinv[i] = rsqrtf((float)(c + 1));  // +1 self loop
    }
    if (blockIdx.x == 0 && tid == 0) row_ptr[n] = E;
}

__global__ void k_fill(const int* __restrict__ src, const int* __restrict__ dst, int E,
                       int* __restrict__ cursor, int* __restrict__ ssorted) {
    int e = blockIdx.x * blockDim.x + threadIdx.x;
    if (e < E) {
        int p = atomicAdd(&cursor[dst[e]], 1);
        ssorted[p] = src[e];
    }
}

// ---------------- GEMM1: h1_pre[n,64] = x[n,256] @ W_enc_gnn[256,64] (fp32) ---------

#define G1_R 16
__global__ __launch_bounds__(256) void k_gemm1(const float* __restrict__ x,
                                               const float* __restrict__ W,
                                               float* __restrict__ out, int n) {
    __shared__ f16 Wh[256 * 64];     // 32 KB
    __shared__ float As[G1_R * 257]; // padded rows, 16.4 KB
    int tid = threadIdx.x;
    for (int i = tid * 4; i < 256 * 64; i += 1024) {
        float4 w = *(const float4*)&W[i];
        Wh[i + 0] = (f16)w.x;
        Wh[i + 1] = (f16)w.y;
        Wh[i + 2] = (f16)w.z;
        Wh[i + 3] = (f16)w.w;
    }
    int row0 = blockIdx.x * G1_R;
    for (int i4 = tid; i4 < G1_R * 64; i4 += 256) {  // 64 float4 per row
        int r = i4 >> 6, k4 = (i4 & 63) * 4;
        int gr = row0 + r;
        float4 xx = {0.f, 0.f, 0.f, 0.f};
        if (gr < n) xx = *(const float4*)&x[(size_t)gr * 256 + k4];
        As[r * 257 + k4 + 0] = xx.x;
        As[r * 257 + k4 + 1] = xx.y;
        As[r * 257 + k4 + 2] = xx.z;
        As[r * 257 + k4 + 3] = xx.w;
    }
    __syncthreads();
    int r = tid >> 4;          // 0..15
    int cg = (tid & 15) * 4;   // col group
    float4 acc = {0.f, 0.f, 0.f, 0.f};
    const float* ap = &As[r * 257];
#pragma unroll 4
    for (int k = 0; k < 256; k++) {
        float a = ap[k];
        half4 w = *(const half4*)&Wh[k * 64 + cg];
        acc.x += a * (float)w.x;
        acc.y += a * (float)w.y;
        acc.z += a * (float)w.z;
        acc.w += a * (float)w.w;
    }
    int gr = row0 + r;
    if (gr < n) *(float4*)&out[(size_t)gr * 64 + cg] = acc;
}

// ---------------- propagation: out[d] = dinv[d]*(sum_s dinv[s]*h[s] + dinv[d]*h[d]) ------
// wave per node, lane = feature (64)

template <bool RELU_BIAS>
__global__ __launch_bounds__(256) void k_prop(const float* __restrict__ hpre,
                                              const int* __restrict__ row_ptr,
                                              const int* __restrict__ ssorted,
                                              const float* __restrict__ dinv,
                                              const float* __restrict__ bias,
                                              float* __restrict__ out, int n) {
    int lane = threadIdx.x & 63, wid = threadIdx.x >> 6;
    int d = blockIdx.x * 4 + wid;
    if (d >= n) return;
    float dd = dinv[d];
    float acc = dd * hpre[(size_t)d * 64 + lane];  // self loop (inner dinv[d])
    int s0 = row_ptr[d], s1 = row_ptr[d + 1];
    for (int base = s0; base < s1; base += 64) {
        int j = base + lane;
        int sl = 0;
        float wl = 0.f;
        if (j < s1) { sl = ssorted[j]; wl = dinv[sl]; }
        int cnt = min(64, s1 - base);
        int i = 0;
        for (; i + 4 <= cnt; i += 4) {
            int a0 = __shfl(sl, i), a1 = __shfl(sl, i + 1);
            int a2 = __shfl(sl, i + 2), a3 = __shfl(sl, i + 3);
            float w0 = __shfl(wl, i), w1 = __shfl(wl, i + 1);
            float w2 = __shfl(wl, i + 2), w3 = __shfl(wl, i + 3);
            float v0 = hpre[(size_t)a0 * 64 + lane];
            float v1 = hpre[(size_t)a1 * 64 + lane];
            float v2 = hpre[(size_t)a2 * 64 + lane];
            float v3 = hpre[(size_t)a3 * 64 + lane];
            acc += w0 * v0; acc += w1 * v1; acc += w2 * v2; acc += w3 * v3;
        }
        for (; i < cnt; i++) {
            int a = __shfl(sl, i);
            float w = __shfl(wl, i);
            acc += w * hpre[(size_t)a * 64 + lane];
        }
    }
    float val = dd * acc;
    if (RELU_BIAS) val = fmaxf(val + bias[lane], 0.f);
    out[(size_t)d * 64 + lane] = val;
}

// ---------------- fused middle (tile-GEMM): 64 nodes per block ----------------
// z = h1@Wz+bz ; pred = z@Wc+bc ; hd = relu(z@Wd+bd). No shuffles: LDS tiles only.

#define MB 64
__global__ __launch_bounds__(256) void k_mid(const float* __restrict__ h1,
                                             const float* __restrict__ Wz, const float* __restrict__ bz,
                                             const float* __restrict__ Wd, const float* __restrict__ bd,
                                             const float* __restrict__ Wc, const float* __restrict__ bc,
                                             float* __restrict__ hd_ws,
                                             float* __restrict__ z_out, float* __restrict__ pred_out,
                                             int n) {
    __shared__ float Hs[MB * 68];    // h1 tile, padded stride 68 (16B-aligned rows)
    __shared__ float Zs[MB * 36];    // z tile, padded stride 36
    __shared__ float Wzs[64 * 32];   // [k][j]
    __shared__ float Wds[32 * 64];   // [k][f]
    __shared__ float Wcs[32 * 4];    // [k][c], padded
    __shared__ float bzs[32], bds[64], bcs[4];
    int tid = threadIdx.x;
    for (int i = tid; i < 64 * 32; i += 256) Wzs[i] = Wz[i];
    for (int i = tid; i < 32 * 64; i += 256) Wds[i] = Wd[i];
    if (tid < 96) Wcs[(tid / 3) * 4 + (tid % 3)] = Wc[tid];
    if (tid < 32) bzs[tid] = bz[tid];
    if (tid < 64) bds[tid] = bd[tid];
    if (tid < 3)  bcs[tid] = bc[tid];
    int row0 = blockIdx.x * MB;
    for (int i4 = tid; i4 < MB * 16; i4 += 256) {
        int r = i4 >> 4, c4 = (i4 & 15) * 4;
        float4 v = {0.f, 0.f, 0.f, 0.f};
        if (row0 + r < n) v = *(const float4*)&h1[(size_t)(row0 + r) * 64 + c4];
        *(float4*)&Hs[r * 68 + c4] = v;
    }
    __syncthreads();

    // phase A: z[node][j] = sum_k Hs[node][k] * Wz[k][j] + bz[j]
    {
        int j = tid & 31, g = tid >> 5;  // 8 node-groups
        float acc[8] = {0.f, 0.f, 0.f, 0.f, 0.f, 0.f, 0.f, 0.f};
        for (int k = 0; k < 64; k++) {
            float wv = Wzs[k * 32 + j];
#pragma unroll
            for (int r = 0; r < 8; r++) acc[r] += Hs[(g + 8 * r) * 68 + k] * wv;
        }
        float bj = bzs[j];
#pragma unroll
        for (int r = 0; r < 8; r++) {
            int node = g + 8 * r;
            float zv = acc[r] + bj;
            Zs[node * 36 + j] = zv;
            if (row0 + node < n) z_out[(size_t)(row0 + node) * 32 + j] = zv;
        }
    }
    __syncthreads();

    // phase B: hd[node][f] = relu(sum_k Zs[node][k] * Wd[k][f] + bd[f])
    {
        int f = tid & 63, g = tid >> 6;  // 4 node-groups
        float acc[16];
#pragma unroll
        for (int r = 0; r < 16; r++) acc[r] = bds[f];
        for (int k = 0; k < 32; k++) {
            float wv = Wds[k * 64 + f];
#pragma unroll
            for (int r = 0; r < 16; r++) acc[r] += Zs[(g + 4 * r) * 36 + k] * wv;
        }
#pragma unroll
        for (int r = 0; r < 16; r++) {
            int node = g + 4 * r;
            if (row0 + node < n) hd_ws[(size_t)(row0 + node) * 64 + f] = fmaxf(acc[r], 0.f);
        }
    }

    // pred: wave 0, one node per lane
    if (tid < 64) {
        int node = tid;
        float pa = bcs[0], pb = bcs[1], pc = bcs[2];
        for (int k = 0; k < 32; k++) {
            float zv = Zs[node * 36 + k];
            pa += zv * Wcs[k * 4 + 0];
            pb += zv * Wcs[k * 4 + 1];
            pc += zv * Wcs[k * 4 + 2];
        }
        if (row0 + node < n) {
            pred_out[(size_t)(row0 + node) * 3 + 0] = pa;
            pred_out[(size_t)(row0 + node) * 3 + 1] = pb;
            pred_out[(size_t)(row0 + node) * 3 + 2] = pc;
        }
    }
}

// ---------------- GEMM5 (64-row tile): x_recon[n,256] = p2[n,64] @ W_dec_gnn[64,256] + b ---
// block = 256 threads, 64 rows. wave w handles rows w+4*rr (rr=0..15), lane = col-group.
// A-reads are wave-uniform broadcasts; W f16 reads are 8B/lane (2-way aliasing, free).

#define G5_R 64
__global__ __launch_bounds__(256, 3) void k_gemm5(const float* __restrict__ A,
                                                  const float* __restrict__ W,
                                                  const float* __restrict__ bias,
                                                  float* __restrict__ out, int n) {
    __shared__ f16 Wh[64 * 256];      // 32 KB, [k][c]
    __shared__ float As[G5_R * 68];   // 17 KB, padded stride 68
    int tid = threadIdx.x;
    // stage W -> f16 LDS (coalesced float4, packed half4 writes)
    for (int i = tid * 4; i < 64 * 256; i += 1024) {
        float4 w = *(const float4*)&W[i];
        half4 h;
        h.x = (f16)w.x; h.y = (f16)w.y; h.z = (f16)w.z; h.w = (f16)w.w;
        *(half4*)&Wh[i] = h;
    }
    // stage A tile (64 rows x 64 cols fp32)
    int row0 = blockIdx.x * G5_R;
    for (int j = tid; j < G5_R * 16; j += 256) {
        int r = j >> 4, c4 = (j & 15) * 4;
        int gr = row0 + r;
        float4 v = {0.f, 0.f, 0.f, 0.f};
        if (gr < n) v = *(const float4*)&A[(size_t)gr * 64 + c4];
        *(float4*)&As[r * 68 + c4] = v;
    }
    __syncthreads();

    int cg = (tid & 63) * 4;  // col group 0..255 step 4
    int g  = tid >> 6;        // wave id -> row phase
    float acc[16][4];
#pragma unroll
    for (int rr = 0; rr < 16; rr++) {
        acc[rr][0] = 0.f; acc[rr][1] = 0.f; acc[rr][2] = 0.f; acc[rr][3] = 0.f;
    }
    for (int k4 = 0; k4 < 16; k4++) {
        int k = k4 * 4;
        half4 w0 = *(const half4*)&Wh[(k + 0) * 256 + cg];
        half4 w1 = *(const half4*)&Wh[(k + 1) * 256 + cg];
        half4 w2 = *(const half4*)&Wh[(k + 2) * 256 + cg];
        half4 w3 = *(const half4*)&Wh[(k + 3) * 256 + cg];
        float4 f0 = {(float)w0.x, (float)w0.y, (float)w0.z, (float)w0.w};
        float4 f1 = {(float)w1.x, (float)w1.y, (float)w1.z, (float)w1.w};
        float4 f2 = {(float)w2.x, (float)w2.y, (float)w2.z, (float)w2.w};
        float4 f3 = {(float)w3.x, (float)w3.y, (float)w3.z, (float)w3.w};
#pragma unroll
        for (int rr = 0; rr < 16; rr++) {
            int row = g + 4 * rr;
            float4 a = *(const float4*)&As[row * 68 + k];
            acc[rr][0] += a.x * f0.x; acc[rr][1] += a.x * f0.y;
            acc[rr][2] += a.x * f0.z; acc[rr][3] += a.x * f0.w;
            acc[rr][0] += a.y * f1.x; acc[rr][1] += a.y * f1.y;
            acc[rr][2] += a.y * f1.z; acc[rr][3] += a.y * f1.w;
            acc[rr][0] += a.z * f2.x; acc[rr][1] += a.z * f2.y;
            acc[rr][2] += a.z * f2.z; acc[rr][3] += a.z * f2.w;
            acc[rr][0] += a.w * f3.x; acc[rr][1] += a.w * f3.y;
            acc[rr][2] += a.w * f3.z; acc[rr][3] += a.w * f3.w;
        }
    }
    float4 b4 = *(const float4*)&bias[cg];
#pragma unroll
    for (int rr = 0; rr < 16; rr++) {
        int gr = row0 + g + 4 * rr;
        if (gr < n) {
            float4 o;
            o.x = acc[rr][0] + b4.x;
            o.y = acc[rr][1] + b4.y;
            o.z = acc[rr][2] + b4.z;
            o.w = acc[rr][3] + b4.w;
            *(float4*)&out[(size_t)gr * 256 + cg] = o;
        }
    }
}

// ---------------- launch ----------------

extern "C" void kernel_launch(void* const* d_in, const int* in_sizes, int n_in,
                              void* d_out, int out_size, void* d_ws, size_t ws_size,
                              hipStream_t stream) {
    const float* x    = (const float*)d_in[0];
    const int*   ei   = (const int*)d_in[1];
    const float* Wenc = (const float*)d_in[3];
    const float* benc = (const float*)d_in[4];
    const float* Wz   = (const float*)d_in[5];
    const float* bz   = (const float*)d_in[6];
    const float* Wd   = (const float*)d_in[7];
    const float* bd   = (const float*)d_in[8];
    const float* Wdec = (const float*)d_in[9];
    const float* bdec = (const float*)d_in[10];
    const float* Wc   = (const float*)d_in[11];
    const float* bc   = (const float*)d_in[12];

    int n = in_sizes[0] / 256;
    int E = in_sizes[1] / 2;
    const int* src = ei;
    const int* dst = ei + E;

    int nb = (n + 255) / 256;  // scan blocks (196 for n=50000)

    // workspace carve-out (~30 MB total)
    char* w = (char*)d_ws;
    size_t off = 0;
    auto alloc = [&](size_t bytes) {
        void* p = w + off;
        off = (off + bytes + 255) & ~(size_t)255;
        return p;
    };
    int*   cnt     = (int*)alloc(sizeof(int) * n);
    int*   row_ptr = (int*)alloc(sizeof(int) * (n + 1));
    int*   cursor  = (int*)alloc(sizeof(int) * n);
    int*   ssorted = (int*)alloc(sizeof(int) * E);
    float* dinv    = (float*)alloc(sizeof(float) * n);
    int*   bsum    = (int*)alloc(sizeof(int) * nb);
    int*   boff    = (int*)alloc(sizeof(int) * nb);
    float* bufA    = (float*)alloc(sizeof(float) * (size_t)n * 64);  // h1pre -> hd
    float* bufB    = (float*)alloc(sizeof(float) * (size_t)n * 64);  // h1 -> p2
    (void)ws_size; (void)n_in; (void)out_size;

    float* out_xr = (float*)d_out;
    float* out_z  = out_xr + (size_t)n * 256;
    float* out_p  = out_z + (size_t)n * 32;

    // CSR build (hierarchical scan)
    k_zero_int<<<dim3(nb), dim3(256), 0, stream>>>(cnt, n);
    k_count<<<dim3((E + 255) / 256), dim3(256), 0, stream>>>(dst, E, cnt);
    k_scan1<<<dim3(nb), dim3(256), 0, stream>>>(cnt, n, bsum);
    k_scan2<<<dim3(1), dim3(256), 0, stream>>>(bsum, nb, boff);
    k_scan3<<<dim3(nb), dim3(256), 0, stream>>>(cnt, n, E, boff, row_ptr, cursor, dinv);
    k_fill<<<dim3((E + 255) / 256), dim3(256), 0, stream>>>(src, dst, E, cursor, ssorted);

    // encoder: bufA = x @ W_enc ; bufB = relu(P bufA + b_enc)
    k_gemm1<<<dim3((n + G1_R - 1) / G1_R), dim3(256), 0, stream>>>(x, Wenc, bufA, n);
    k_prop<true><<<dim3((n + 3) / 4), dim3(256), 0, stream>>>(bufA, row_ptr, ssorted, dinv, benc, bufB, n);

    // middle: z (out), pred (out), hd -> bufA
    k_mid<<<dim3((n + MB - 1) / MB), dim3(256), 0, stream>>>(bufB, Wz, bz, Wd, bd, Wc, bc,
                                                             bufA, out_z, out_p, n);

    // decoder (reassociated): bufB = P bufA ; x_recon = bufB @ W_dec + b_dec
    k_prop<false><<<dim3((n + 3) / 4), dim3(256), 0, stream>>>(bufA, row_ptr, ssorted, dinv, benc, bufB, n);
    k_gemm5<<<dim3((n + G5_R - 1) / G5_R), dim3(256), 0, stream>>>(bufB, Wdec, bdec, out_xr, n);
}

// Round 6
// 375.959 us; speedup vs baseline: 1.7884x; 1.0798x over previous
//
#include <hip/hip_runtime.h>
#include <hip/hip_bf16.h>
#include <stdint.h>

typedef _Float16 f16;
typedef _Float16 half4 __attribute__((ext_vector_type(4)));
typedef _Float16 f16x8 __attribute__((ext_vector_type(8)));
typedef float f32x4 __attribute__((ext_vector_type(4)));

// ---------------- CSR build ----------------

__global__ void k_zero_int(int* __restrict__ p, int n) {
    int i = blockIdx.x * blockDim.x + threadIdx.x;
    if (i < n) p[i] = 0;
}

__global__ void k_count(const int* __restrict__ dst, int E, int* __restrict__ cnt) {
    int e = blockIdx.x * blockDim.x + threadIdx.x;
    if (e < E) atomicAdd(&cnt[dst[e]], 1);
}

// phase 1: per-block (256-wide) reduction of cnt -> bsum[block]
__global__ __launch_bounds__(256) void k_scan1(const int* __restrict__ cnt, int n,
                                               int* __restrict__ bsum) {
    __shared__ int red[256];
    int tid = threadIdx.x;
    int i = blockIdx.x * 256 + tid;
    red[tid] = (i < n) ? cnt[i] : 0;
    __syncthreads();
    for (int o = 128; o > 0; o >>= 1) {
        if (tid < o) red[tid] += red[tid + o];
        __syncthreads();
    }
    if (tid == 0) bsum[blockIdx.x] = red[0];
}

// phase 2: single block exclusive scan of bsum (nb <= 256)
__global__ __launch_bounds__(256) void k_scan2(const int* __restrict__ bsum, int nb,
                                               int* __restrict__ boff) {
    __shared__ int s[256];
    int tid = threadIdx.x;
    int v = (tid < nb) ? bsum[tid] : 0;
    s[tid] = v;
    __syncthreads();
    for (int o = 1; o < 256; o <<= 1) {
        int t = (tid >= o) ? s[tid - o] : 0;
        __syncthreads();
        s[tid] += t;
        __syncthreads();
    }
    if (tid < nb) boff[tid] = s[tid] - v;  // exclusive
}

// phase 3: in-block exclusive scan + block offset -> row_ptr/cursor, dinv
__global__ __launch_bounds__(256) void k_scan3(const int* __restrict__ cnt, int n, int E,
                                               const int* __restrict__ boff,
                                               int* __restrict__ row_ptr, int* __restrict__ cursor,
                                               float* __restrict__ dinv) {
    __shared__ int s[256];
    int tid = threadIdx.x;
    int i = blockIdx.x * 256 + tid;
    int c = (i < n) ? cnt[i] : 0;
    s[tid] = c;
    __syncthreads();
    for (int o = 1; o < 256; o <<= 1) {
        int t = (tid >= o) ? s[tid - o] : 0;
        __syncthreads();
        s[tid] += t;
        __syncthreads();
    }
    if (i < n) {
        int excl = boff[blockIdx.x] + s[tid] - c;
        row_ptr[i] = excl;
        cursor[i] = excl;
        dinv[i] = rsqrtf((float)(c + 1));  // +1 self loop
    }
    if (blockIdx.x == 0 && tid == 0) row_ptr[n] = E;
}

__global__ void k_fill(const int* __restrict__ src, const int* __restrict__ dst, int E,
                       int* __restrict__ cursor, int* __restrict__ ssorted) {
    int e = blockIdx.x * blockDim.x + threadIdx.x;
    if (e < E) {
        int p = atomicAdd(&cursor[dst[e]], 1);
        ssorted[p] = src[e];
    }
}

// ---------------- GEMM1 (MFMA): h1_pre[n,64] = x[n,256] @ W_enc_gnn[256,64] ----------
// 64-row tile per block; v_mfma_f32_16x16x32_f16. W staged in B-fragment order (WB),
// A staged as f16 in two K=128 halves (stride 136 padded). ~50 KB LDS -> 3 blocks/CU.
// Layouts (verified): A[m=lane&15][k=(lane>>4)*8+j]; B[k=(lane>>4)*8+j][n=lane&15];
// D: col=lane&15, row=(lane>>4)*4+reg.

#define G1M_R 64
__global__ __launch_bounds__(256) void k_gemm1(const float* __restrict__ x,
                                               const float* __restrict__ W,
                                               float* __restrict__ out, int n) {
    __shared__ __attribute__((aligned(16))) f16 WB[4 * 8 * 64 * 8];  // [t][ks][lane][8] = 32 KB
    __shared__ __attribute__((aligned(16))) f16 Ah[64 * 136];        // [row][k-half], 17 KB
    int tid = threadIdx.x;
    int row0 = blockIdx.x * G1M_R;

    // stage W -> fragment order (once): element (k,c): t=c>>4, ks=k>>5, q=(k&31)>>3,
    // j=k&7, lane=q*16+(c&15)  ->  WB[(((t*8+ks)*64 + lane)*8 + j]
    for (int i = tid; i < 4096; i += 256) {
        int k = i >> 4, c4 = (i & 15) * 4;
        float4 w = *(const float4*)&W[k * 64 + c4];
        int t = c4 >> 4, ks = k >> 5, q = (k & 31) >> 3, j = k & 7;
        int base = (((t * 8 + ks) * 64 + q * 16 + (c4 & 15)) * 8) + j;
        WB[base + 0]  = (f16)w.x;
        WB[base + 8]  = (f16)w.y;
        WB[base + 16] = (f16)w.z;
        WB[base + 24] = (f16)w.w;
    }

    int lane = tid & 63, w = tid >> 6;
    int m = lane & 15, q = lane >> 4;

    f32x4 acc[4];
#pragma unroll
    for (int t = 0; t < 4; t++) acc[t] = (f32x4){0.f, 0.f, 0.f, 0.f};

    for (int h = 0; h < 2; h++) {
        // stage A half h: k = 128h .. 128h+127 (zero-pad rows >= n)
        __syncthreads();
        for (int i = tid; i < 2048; i += 256) {
            int r = i >> 5, k4 = (i & 31) * 4;
            float4 v = {0.f, 0.f, 0.f, 0.f};
            if (row0 + r < n) v = *(const float4*)&x[(size_t)(row0 + r) * 256 + 128 * h + k4];
            half4 hv;
            hv.x = (f16)v.x; hv.y = (f16)v.y; hv.z = (f16)v.z; hv.w = (f16)v.w;
            *(half4*)&Ah[r * 136 + k4] = hv;
        }
        __syncthreads();
#pragma unroll
        for (int ksl = 0; ksl < 4; ksl++) {
            int ks = 4 * h + ksl;
            f16x8 a = *(const f16x8*)&Ah[(16 * w + m) * 136 + 32 * ksl + 8 * q];
#pragma unroll
            for (int t = 0; t < 4; t++) {
                f16x8 b = *(const f16x8*)&WB[((t * 8 + ks) * 64 + lane) * 8];
                acc[t] = __builtin_amdgcn_mfma_f32_16x16x32_f16(a, b, acc[t], 0, 0, 0);
            }
        }
    }

    // epilogue: lane holds rows (16w + 4q + r), col = 16t + m
#pragma unroll
    for (int t = 0; t < 4; t++) {
#pragma unroll
        for (int r = 0; r < 4; r++) {
            int gr = row0 + 16 * w + 4 * q + r;
            if (gr < n) out[(size_t)gr * 64 + 16 * t + m] = acc[t][r];
        }
    }
}

// ---------------- propagation: out[d] = dinv[d]*(sum_s dinv[s]*h[s] + dinv[d]*h[d]) ------
// wave per node, lane = feature (64)

template <bool RELU_BIAS>
__global__ __launch_bounds__(256) void k_prop(const float* __restrict__ hpre,
                                              const int* __restrict__ row_ptr,
                                              const int* __restrict__ ssorted,
                                              const float* __restrict__ dinv,
                                              const float* __restrict__ bias,
                                              float* __restrict__ out, int n) {
    int lane = threadIdx.x & 63, wid = threadIdx.x >> 6;
    int d = blockIdx.x * 4 + wid;
    if (d >= n) return;
    float dd = dinv[d];
    float acc = dd * hpre[(size_t)d * 64 + lane];  // self loop (inner dinv[d])
    int s0 = row_ptr[d], s1 = row_ptr[d + 1];
    for (int base = s0; base < s1; base += 64) {
        int j = base + lane;
        int sl = 0;
        float wl = 0.f;
        if (j < s1) { sl = ssorted[j]; wl = dinv[sl]; }
        int cnt = min(64, s1 - base);
        int i = 0;
        for (; i + 4 <= cnt; i += 4) {
            int a0 = __shfl(sl, i), a1 = __shfl(sl, i + 1);
            int a2 = __shfl(sl, i + 2), a3 = __shfl(sl, i + 3);
            float w0 = __shfl(wl, i), w1 = __shfl(wl, i + 1);
            float w2 = __shfl(wl, i + 2), w3 = __shfl(wl, i + 3);
            float v0 = hpre[(size_t)a0 * 64 + lane];
            float v1 = hpre[(size_t)a1 * 64 + lane];
            float v2 = hpre[(size_t)a2 * 64 + lane];
            float v3 = hpre[(size_t)a3 * 64 + lane];
            acc += w0 * v0; acc += w1 * v1; acc += w2 * v2; acc += w3 * v3;
        }
        for (; i < cnt; i++) {
            int a = __shfl(sl, i);
            float w = __shfl(wl, i);
            acc += w * hpre[(size_t)a * 64 + lane];
        }
    }
    float val = dd * acc;
    if (RELU_BIAS) val = fmaxf(val + bias[lane], 0.f);
    out[(size_t)d * 64 + lane] = val;
}

// ---------------- fused middle (tile-GEMM): 64 nodes per block ----------------
// z = h1@Wz+bz ; pred = z@Wc+bc ; hd = relu(z@Wd+bd). No shuffles: LDS tiles only.

#define MB 64
__global__ __launch_bounds__(256) void k_mid(const float* __restrict__ h1,
                                             const float* __restrict__ Wz, const float* __restrict__ bz,
                                             const float* __restrict__ Wd, const float* __restrict__ bd,
                                             const float* __restrict__ Wc, const float* __restrict__ bc,
                                             float* __restrict__ hd_ws,
                                             float* __restrict__ z_out, float* __restrict__ pred_out,
                                             int n) {
    __shared__ float Hs[MB * 68];    // h1 tile, padded stride 68 (16B-aligned rows)
    __shared__ float Zs[MB * 36];    // z tile, padded stride 36
    __shared__ float Wzs[64 * 32];   // [k][j]
    __shared__ float Wds[32 * 64];   // [k][f]
    __shared__ float Wcs[32 * 4];    // [k][c], padded
    __shared__ float bzs[32], bds[64], bcs[4];
    int tid = threadIdx.x;
    for (int i = tid; i < 64 * 32; i += 256) Wzs[i] = Wz[i];
    for (int i = tid; i < 32 * 64; i += 256) Wds[i] = Wd[i];
    if (tid < 96) Wcs[(tid / 3) * 4 + (tid % 3)] = Wc[tid];
    if (tid < 32) bzs[tid] = bz[tid];
    if (tid < 64) bds[tid] = bd[tid];
    if (tid < 3)  bcs[tid] = bc[tid];
    int row0 = blockIdx.x * MB;
    for (int i4 = tid; i4 < MB * 16; i4 += 256) {
        int r = i4 >> 4, c4 = (i4 & 15) * 4;
        float4 v = {0.f, 0.f, 0.f, 0.f};
        if (row0 + r < n) v = *(const float4*)&h1[(size_t)(row0 + r) * 64 + c4];
        *(float4*)&Hs[r * 68 + c4] = v;
    }
    __syncthreads();

    // phase A: z[node][j] = sum_k Hs[node][k] * Wz[k][j] + bz[j]
    {
        int j = tid & 31, g = tid >> 5;  // 8 node-groups
        float acc[8] = {0.f, 0.f, 0.f, 0.f, 0.f, 0.f, 0.f, 0.f};
        for (int k = 0; k < 64; k++) {
            float wv = Wzs[k * 32 + j];
#pragma unroll
            for (int r = 0; r < 8; r++) acc[r] += Hs[(g + 8 * r) * 68 + k] * wv;
        }
        float bj = bzs[j];
#pragma unroll
        for (int r = 0; r < 8; r++) {
            int node = g + 8 * r;
            float zv = acc[r] + bj;
            Zs[node * 36 + j] = zv;
            if (row0 + node < n) z_out[(size_t)(row0 + node) * 32 + j] = zv;
        }
    }
    __syncthreads();

    // phase B: hd[node][f] = relu(sum_k Zs[node][k] * Wd[k][f] + bd[f])
    {
        int f = tid & 63, g = tid >> 6;  // 4 node-groups
        float acc[16];
#pragma unroll
        for (int r = 0; r < 16; r++) acc[r] = bds[f];
        for (int k = 0; k < 32; k++) {
            float wv = Wds[k * 64 + f];
#pragma unroll
            for (int r = 0; r < 16; r++) acc[r] += Zs[(g + 4 * r) * 36 + k] * wv;
        }
#pragma unroll
        for (int r = 0; r < 16; r++) {
            int node = g + 4 * r;
            if (row0 + node < n) hd_ws[(size_t)(row0 + node) * 64 + f] = fmaxf(acc[r], 0.f);
        }
    }

    // pred: wave 0, one node per lane
    if (tid < 64) {
        int node = tid;
        float pa = bcs[0], pb = bcs[1], pc = bcs[2];
        for (int k = 0; k < 32; k++) {
            float zv = Zs[node * 36 + k];
            pa += zv * Wcs[k * 4 + 0];
            pb += zv * Wcs[k * 4 + 1];
            pc += zv * Wcs[k * 4 + 2];
        }
        if (row0 + node < n) {
            pred_out[(size_t)(row0 + node) * 3 + 0] = pa;
            pred_out[(size_t)(row0 + node) * 3 + 1] = pb;
            pred_out[(size_t)(row0 + node) * 3 + 2] = pc;
        }
    }
}

// ---------------- GEMM5 (64-row tile): x_recon[n,256] = p2[n,64] @ W_dec_gnn[64,256] + b ---

#define G5_R 64
__global__ __launch_bounds__(256, 3) void k_gemm5(const float* __restrict__ A,
                                                  const float* __restrict__ W,
                                                  const float* __restrict__ bias,
                                                  float* __restrict__ out, int n) {
    __shared__ f16 Wh[64 * 256];      // 32 KB, [k][c]
    __shared__ float As[G5_R * 68];   // 17 KB, padded stride 68
    int tid = threadIdx.x;
    // stage W -> f16 LDS (coalesced float4, packed half4 writes)
    for (int i = tid * 4; i < 64 * 256; i += 1024) {
        float4 w = *(const float4*)&W[i];
        half4 h;
        h.x = (f16)w.x; h.y = (f16)w.y; h.z = (f16)w.z; h.w = (f16)w.w;
        *(half4*)&Wh[i] = h;
    }
    // stage A tile (64 rows x 64 cols fp32)
    int row0 = blockIdx.x * G5_R;
    for (int j = tid; j < G5_R * 16; j += 256) {
        int r = j >> 4, c4 = (j & 15) * 4;
        int gr = row0 + r;
        float4 v = {0.f, 0.f, 0.f, 0.f};
        if (gr < n) v = *(const float4*)&A[(size_t)gr * 64 + c4];
        *(float4*)&As[r * 68 + c4] = v;
    }
    __syncthreads();

    int cg = (tid & 63) * 4;  // col group 0..255 step 4
    int g  = tid >> 6;        // wave id -> row phase
    float acc[16][4];
#pragma unroll
    for (int rr = 0; rr < 16; rr++) {
        acc[rr][0] = 0.f; acc[rr][1] = 0.f; acc[rr][2] = 0.f; acc[rr][3] = 0.f;
    }
    for (int k4 = 0; k4 < 16; k4++) {
        int k = k4 * 4;
        half4 w0 = *(const half4*)&Wh[(k + 0) * 256 + cg];
        half4 w1 = *(const half4*)&Wh[(k + 1) * 256 + cg];
        half4 w2 = *(const half4*)&Wh[(k + 2) * 256 + cg];
        half4 w3 = *(const half4*)&Wh[(k + 3) * 256 + cg];
        float4 f0 = {(float)w0.x, (float)w0.y, (float)w0.z, (float)w0.w};
        float4 f1 = {(float)w1.x, (float)w1.y, (float)w1.z, (float)w1.w};
        float4 f2 = {(float)w2.x, (float)w2.y, (float)w2.z, (float)w2.w};
        float4 f3 = {(float)w3.x, (float)w3.y, (float)w3.z, (float)w3.w};
#pragma unroll
        for (int rr = 0; rr < 16; rr++) {
            int row = g + 4 * rr;
            float4 a = *(const float4*)&As[row * 68 + k];
            acc[rr][0] += a.x * f0.x; acc[rr][1] += a.x * f0.y;
            acc[rr][2] += a.x * f0.z; acc[rr][3] += a.x * f0.w;
            acc[rr][0] += a.y * f1.x; acc[rr][1] += a.y * f1.y;
            acc[rr][2] += a.y * f1.z; acc[rr][3] += a.y * f1.w;
            acc[rr][0] += a.z * f2.x; acc[rr][1] += a.z * f2.y;
            acc[rr][2] += a.z * f2.z; acc[rr][3] += a.z * f2.w;
            acc[rr][0] += a.w * f3.x; acc[rr][1] += a.w * f3.y;
            acc[rr][2] += a.w * f3.z; acc[rr][3] += a.w * f3.w;
        }
    }
    float4 b4 = *(const float4*)&bias[cg];
#pragma unroll
    for (int rr = 0; rr < 16; rr++) {
        int gr = row0 + g + 4 * rr;
        if (gr < n) {
            float4 o;
            o.x = acc[rr][0] + b4.x;
            o.y = acc[rr][1] + b4.y;
            o.z = acc[rr][2] + b4.z;
            o.w = acc[rr][3] + b4.w;
            *(float4*)&out[(size_t)gr * 256 + cg] = o;
        }
    }
}

// ---------------- launch ----------------

extern "C" void kernel_launch(void* const* d_in, const int* in_sizes, int n_in,
                              void* d_out, int out_size, void* d_ws, size_t ws_size,
                              hipStream_t stream) {
    const float* x    = (const float*)d_in[0];
    const int*   ei   = (const int*)d_in[1];
    const float* Wenc = (const float*)d_in[3];
    const float* benc = (const float*)d_in[4];
    const float* Wz   = (const float*)d_in[5];
    const float* bz   = (const float*)d_in[6];
    const float* Wd   = (const float*)d_in[7];
    const float* bd   = (const float*)d_in[8];
    const float* Wdec = (const float*)d_in[9];
    const float* bdec = (const float*)d_in[10];
    const float* Wc   = (const float*)d_in[11];
    const float* bc   = (const float*)d_in[12];

    int n = in_sizes[0] / 256;
    int E = in_sizes[1] / 2;
    const int* src = ei;
    const int* dst = ei + E;

    int nb = (n + 255) / 256;  // scan blocks (196 for n=50000)

    // workspace carve-out (~30 MB total)
    char* w = (char*)d_ws;
    size_t off = 0;
    auto alloc = [&](size_t bytes) {
        void* p = w + off;
        off = (off + bytes + 255) & ~(size_t)255;
        return p;
    };
    int*   cnt     = (int*)alloc(sizeof(int) * n);
    int*   row_ptr = (int*)alloc(sizeof(int) * (n + 1));
    int*   cursor  = (int*)alloc(sizeof(int) * n);
    int*   ssorted = (int*)alloc(sizeof(int) * E);
    float* dinv    = (float*)alloc(sizeof(float) * n);
    int*   bsum    = (int*)alloc(sizeof(int) * nb);
    int*   boff    = (int*)alloc(sizeof(int) * nb);
    float* bufA    = (float*)alloc(sizeof(float) * (size_t)n * 64);  // h1pre -> hd
    float* bufB    = (float*)alloc(sizeof(float) * (size_t)n * 64);  // h1 -> p2
    (void)ws_size; (void)n_in; (void)out_size;

    float* out_xr = (float*)d_out;
    float* out_z  = out_xr + (size_t)n * 256;
    float* out_p  = out_z + (size_t)n * 32;

    // CSR build (hierarchical scan)
    k_zero_int<<<dim3(nb), dim3(256), 0, stream>>>(cnt, n);
    k_count<<<dim3((E + 255) / 256), dim3(256), 0, stream>>>(dst, E, cnt);
    k_scan1<<<dim3(nb), dim3(256), 0, stream>>>(cnt, n, bsum);
    k_scan2<<<dim3(1), dim3(256), 0, stream>>>(bsum, nb, boff);
    k_scan3<<<dim3(nb), dim3(256), 0, stream>>>(cnt, n, E, boff, row_ptr, cursor, dinv);
    k_fill<<<dim3((E + 255) / 256), dim3(256), 0, stream>>>(src, dst, E, cursor, ssorted);

    // encoder: bufA = x @ W_enc ; bufB = relu(P bufA + b_enc)
    k_gemm1<<<dim3((n + G1M_R - 1) / G1M_R), dim3(256), 0, stream>>>(x, Wenc, bufA, n);
    k_prop<true><<<dim3((n + 3) / 4), dim3(256), 0, stream>>>(bufA, row_ptr, ssorted, dinv, benc, bufB, n);

    // middle: z (out), pred (out), hd -> bufA
    k_mid<<<dim3((n + MB - 1) / MB), dim3(256), 0, stream>>>(bufB, Wz, bz, Wd, bd, Wc, bc,
                                                             bufA, out_z, out_p, n);

    // decoder (reassociated): bufB = P bufA ; x_recon = bufB @ W_dec + b_dec
    k_prop<false><<<dim3((n + 3) / 4), dim3(256), 0, stream>>>(bufA, row_ptr, ssorted, dinv, benc, bufB, n);
    k_gemm5<<<dim3((n + G5_R - 1) / G5_R), dim3(256), 0, stream>>>(bufB, Wdec, bdec, out_xr, n);
}

// Round 7
// 343.801 us; speedup vs baseline: 1.9557x; 1.0935x over previous
//
#include <hip/hip_runtime.h>
#include <hip/hip_bf16.h>
#include <stdint.h>

typedef _Float16 f16;
typedef _Float16 half4 __attribute__((ext_vector_type(4)));
typedef _Float16 f16x8 __attribute__((ext_vector_type(8)));
typedef float f32x4 __attribute__((ext_vector_type(4)));

// ---------------- CSR build ----------------

__global__ void k_zero_int(int* __restrict__ p, int n) {
    int i = blockIdx.x * blockDim.x + threadIdx.x;
    if (i < n) p[i] = 0;
}

__global__ void k_count(const int* __restrict__ dst, int E, int* __restrict__ cnt) {
    int e = blockIdx.x * blockDim.x + threadIdx.x;
    if (e < E) atomicAdd(&cnt[dst[e]], 1);
}

// phase 1: per-block (256-wide) reduction of cnt -> bsum[block]
__global__ __launch_bounds__(256) void k_scan1(const int* __restrict__ cnt, int n,
                                               int* __restrict__ bsum) {
    __shared__ int red[256];
    int tid = threadIdx.x;
    int i = blockIdx.x * 256 + tid;
    red[tid] = (i < n) ? cnt[i] : 0;
    __syncthreads();
    for (int o = 128; o > 0; o >>= 1) {
        if (tid < o) red[tid] += red[tid + o];
        __syncthreads();
    }
    if (tid == 0) bsum[blockIdx.x] = red[0];
}

// phase 2: single block exclusive scan of bsum (nb <= 256)
__global__ __launch_bounds__(256) void k_scan2(const int* __restrict__ bsum, int nb,
                                               int* __restrict__ boff) {
    __shared__ int s[256];
    int tid = threadIdx.x;
    int v = (tid < nb) ? bsum[tid] : 0;
    s[tid] = v;
    __syncthreads();
    for (int o = 1; o < 256; o <<= 1) {
        int t = (tid >= o) ? s[tid - o] : 0;
        __syncthreads();
        s[tid] += t;
        __syncthreads();
    }
    if (tid < nb) boff[tid] = s[tid] - v;  // exclusive
}

// phase 3: in-block exclusive scan + block offset -> row_ptr/cursor, dinv
__global__ __launch_bounds__(256) void k_scan3(const int* __restrict__ cnt, int n, int E,
                                               const int* __restrict__ boff,
                                               int* __restrict__ row_ptr, int* __restrict__ cursor,
                                               float* __restrict__ dinv) {
    __shared__ int s[256];
    int tid = threadIdx.x;
    int i = blockIdx.x * 256 + tid;
    int c = (i < n) ? cnt[i] : 0;
    s[tid] = c;
    __syncthreads();
    for (int o = 1; o < 256; o <<= 1) {
        int t = (tid >= o) ? s[tid - o] : 0;
        __syncthreads();
        s[tid] += t;
        __syncthreads();
    }
    if (i < n) {
        int excl = boff[blockIdx.x] + s[tid] - c;
        row_ptr[i] = excl;
        cursor[i] = excl;
        dinv[i] = rsqrtf((float)(c + 1));  // +1 self loop
    }
    if (blockIdx.x == 0 && tid == 0) row_ptr[n] = E;
}

__global__ void k_fill(const int* __restrict__ src, const int* __restrict__ dst, int E,
                       int* __restrict__ cursor, int* __restrict__ ssorted) {
    int e = blockIdx.x * blockDim.x + threadIdx.x;
    if (e < E) {
        int p = atomicAdd(&cursor[dst[e]], 1);
        ssorted[p] = src[e];
    }
}

// ---------------- GEMM1 (MFMA): h1_pre[n,64] = x[n,256] @ W_enc_gnn[256,64] ----------

#define G1M_R 64
__global__ __launch_bounds__(256) void k_gemm1(const float* __restrict__ x,
                                               const float* __restrict__ W,
                                               float* __restrict__ out, int n) {
    __shared__ __attribute__((aligned(16))) f16 WB[4 * 8 * 64 * 8];  // [t][ks][lane][8] = 32 KB
    __shared__ __attribute__((aligned(16))) f16 Ah[64 * 136];        // [row][k-half], 17 KB
    int tid = threadIdx.x;
    int row0 = blockIdx.x * G1M_R;

    for (int i = tid; i < 4096; i += 256) {
        int k = i >> 4, c4 = (i & 15) * 4;
        float4 w = *(const float4*)&W[k * 64 + c4];
        int t = c4 >> 4, ks = k >> 5, q = (k & 31) >> 3, j = k & 7;
        int base = (((t * 8 + ks) * 64 + q * 16 + (c4 & 15)) * 8) + j;
        WB[base + 0]  = (f16)w.x;
        WB[base + 8]  = (f16)w.y;
        WB[base + 16] = (f16)w.z;
        WB[base + 24] = (f16)w.w;
    }

    int lane = tid & 63, w = tid >> 6;
    int m = lane & 15, q = lane >> 4;

    f32x4 acc[4];
#pragma unroll
    for (int t = 0; t < 4; t++) acc[t] = (f32x4){0.f, 0.f, 0.f, 0.f};

    for (int h = 0; h < 2; h++) {
        __syncthreads();
        for (int i = tid; i < 2048; i += 256) {
            int r = i >> 5, k4 = (i & 31) * 4;
            float4 v = {0.f, 0.f, 0.f, 0.f};
            if (row0 + r < n) v = *(const float4*)&x[(size_t)(row0 + r) * 256 + 128 * h + k4];
            half4 hv;
            hv.x = (f16)v.x; hv.y = (f16)v.y; hv.z = (f16)v.z; hv.w = (f16)v.w;
            *(half4*)&Ah[r * 136 + k4] = hv;
        }
        __syncthreads();
#pragma unroll
        for (int ksl = 0; ksl < 4; ksl++) {
            int ks = 4 * h + ksl;
            f16x8 a = *(const f16x8*)&Ah[(16 * w + m) * 136 + 32 * ksl + 8 * q];
#pragma unroll
            for (int t = 0; t < 4; t++) {
                f16x8 b = *(const f16x8*)&WB[((t * 8 + ks) * 64 + lane) * 8];
                acc[t] = __builtin_amdgcn_mfma_f32_16x16x32_f16(a, b, acc[t], 0, 0, 0);
            }
        }
    }

#pragma unroll
    for (int t = 0; t < 4; t++) {
#pragma unroll
        for (int r = 0; r < 4; r++) {
            int gr = row0 + 16 * w + 4 * q + r;
            if (gr < n) out[(size_t)gr * 64 + 16 * t + m] = acc[t][r];
        }
    }
}

// ---------------- propagation: out[d] = dinv[d]*(sum_s dinv[s]*h[s] + dinv[d]*h[d]) ------

template <bool RELU_BIAS>
__global__ __launch_bounds__(256) void k_prop(const float* __restrict__ hpre,
                                              const int* __restrict__ row_ptr,
                                              const int* __restrict__ ssorted,
                                              const float* __restrict__ dinv,
                                              const float* __restrict__ bias,
                                              float* __restrict__ out, int n) {
    int lane = threadIdx.x & 63, wid = threadIdx.x >> 6;
    int d = blockIdx.x * 4 + wid;
    if (d >= n) return;
    float dd = dinv[d];
    float acc = dd * hpre[(size_t)d * 64 + lane];  // self loop (inner dinv[d])
    int s0 = row_ptr[d], s1 = row_ptr[d + 1];
    for (int base = s0; base < s1; base += 64) {
        int j = base + lane;
        int sl = 0;
        float wl = 0.f;
        if (j < s1) { sl = ssorted[j]; wl = dinv[sl]; }
        int cnt = min(64, s1 - base);
        int i = 0;
        for (; i + 4 <= cnt; i += 4) {
            int a0 = __shfl(sl, i), a1 = __shfl(sl, i + 1);
            int a2 = __shfl(sl, i + 2), a3 = __shfl(sl, i + 3);
            float w0 = __shfl(wl, i), w1 = __shfl(wl, i + 1);
            float w2 = __shfl(wl, i + 2), w3 = __shfl(wl, i + 3);
            float v0 = hpre[(size_t)a0 * 64 + lane];
            float v1 = hpre[(size_t)a1 * 64 + lane];
            float v2 = hpre[(size_t)a2 * 64 + lane];
            float v3 = hpre[(size_t)a3 * 64 + lane];
            acc += w0 * v0; acc += w1 * v1; acc += w2 * v2; acc += w3 * v3;
        }
        for (; i < cnt; i++) {
            int a = __shfl(sl, i);
            float w = __shfl(wl, i);
            acc += w * hpre[(size_t)a * 64 + lane];
        }
    }
    float val = dd * acc;
    if (RELU_BIAS) val = fmaxf(val + bias[lane], 0.f);
    out[(size_t)d * 64 + lane] = val;
}

// ---------------- fused middle (MFMA): 64 nodes per block ----------------
// z = h1@Wz+bz (fp32 out + f16 LDS copy); hd = relu(z@Wd+bd); pred = z@Wc+bc.
// Fragment layouts identical to k_gemm1 (verified): A[m=lane&15][k=8q+j(+32ks)],
// B[k][n=lane&15], D col=lane&15 row=4q+reg.

#define MB 64
__global__ __launch_bounds__(256) void k_mid(const float* __restrict__ h1,
                                             const float* __restrict__ Wz, const float* __restrict__ bz,
                                             const float* __restrict__ Wd, const float* __restrict__ bd,
                                             const float* __restrict__ Wc, const float* __restrict__ bc,
                                             float* __restrict__ hd_ws,
                                             float* __restrict__ z_out, float* __restrict__ pred_out,
                                             int n) {
    __shared__ __attribute__((aligned(16))) f16 Ah[64 * 72];       // h1 f16, stride 72
    __shared__ __attribute__((aligned(16))) f16 Zh[64 * 40];       // z f16, stride 40
    __shared__ __attribute__((aligned(16))) f16 WzB[2 * 2 * 64 * 8];  // [(t*2+ks)][lane][j]
    __shared__ __attribute__((aligned(16))) f16 WdB[4 * 64 * 8];      // [t][lane][j]
    __shared__ float Wcs[32 * 4];
    __shared__ float bzs[32], bds[64], bcs[4];
    int tid = threadIdx.x;
    int row0 = blockIdx.x * MB;

    // stage Wz [64k x 32c] -> B-frag order
    for (int i = tid; i < 2048; i += 256) {
        int k = i >> 5, c = i & 31;
        int ks = k >> 5, q = (k >> 3) & 3, j = k & 7;
        int t = c >> 4, ln = q * 16 + (c & 15);
        WzB[((t * 2 + ks) * 64 + ln) * 8 + j] = (f16)Wz[i];
    }
    // stage Wd [32k x 64c] -> B-frag order
    for (int i = tid; i < 2048; i += 256) {
        int k = i >> 6, c = i & 63;
        int q = k >> 3, j = k & 7;
        int t = c >> 4, ln = q * 16 + (c & 15);
        WdB[(t * 64 + ln) * 8 + j] = (f16)Wd[i];
    }
    if (tid < 96) Wcs[(tid / 3) * 4 + (tid % 3)] = Wc[tid];
    if (tid < 32) bzs[tid] = bz[tid];
    if (tid < 64) bds[tid] = bd[tid];
    if (tid < 3)  bcs[tid] = bc[tid];
    // stage h1 tile -> f16
    for (int i = tid; i < 1024; i += 256) {
        int r = i >> 4, c4 = (i & 15) * 4;
        float4 v = {0.f, 0.f, 0.f, 0.f};
        if (row0 + r < n) v = *(const float4*)&h1[(size_t)(row0 + r) * 64 + c4];
        half4 hv;
        hv.x = (f16)v.x; hv.y = (f16)v.y; hv.z = (f16)v.z; hv.w = (f16)v.w;
        *(half4*)&Ah[r * 72 + c4] = hv;
    }
    __syncthreads();

    int lane = tid & 63, w = tid >> 6;
    int m = lane & 15, q = lane >> 4;

    // phase A: z = H @ Wz
    f32x4 za[2];
    za[0] = (f32x4){0.f, 0.f, 0.f, 0.f};
    za[1] = (f32x4){0.f, 0.f, 0.f, 0.f};
#pragma unroll
    for (int ks = 0; ks < 2; ks++) {
        f16x8 a = *(const f16x8*)&Ah[(16 * w + m) * 72 + 32 * ks + 8 * q];
#pragma unroll
        for (int t = 0; t < 2; t++) {
            f16x8 b = *(const f16x8*)&WzB[((t * 2 + ks) * 64 + lane) * 8];
            za[t] = __builtin_amdgcn_mfma_f32_16x16x32_f16(a, b, za[t], 0, 0, 0);
        }
    }
#pragma unroll
    for (int t = 0; t < 2; t++) {
        float bj = bzs[16 * t + m];
#pragma unroll
        for (int r = 0; r < 4; r++) {
            int node = 16 * w + 4 * q + r;
            float zv = za[t][r] + bj;
            Zh[node * 40 + 16 * t + m] = (f16)zv;
            if (row0 + node < n) z_out[(size_t)(row0 + node) * 32 + 16 * t + m] = zv;
        }
    }
    __syncthreads();

    // phase B: hd = relu(Z @ Wd + bd)
    f16x8 a2 = *(const f16x8*)&Zh[(16 * w + m) * 40 + 8 * q];
    f32x4 hb[4];
#pragma unroll
    for (int t = 0; t < 4; t++) {
        f16x8 b = *(const f16x8*)&WdB[(t * 64 + lane) * 8];
        f32x4 zero = (f32x4){0.f, 0.f, 0.f, 0.f};
        hb[t] = __builtin_amdgcn_mfma_f32_16x16x32_f16(a2, b, zero, 0, 0, 0);
    }
#pragma unroll
    for (int t = 0; t < 4; t++) {
        float bf = bds[16 * t + m];
#pragma unroll
        for (int r = 0; r < 4; r++) {
            int node = 16 * w + 4 * q + r;
            if (row0 + node < n)
                hd_ws[(size_t)(row0 + node) * 64 + 16 * t + m] = fmaxf(hb[t][r] + bf, 0.f);
        }
    }

    // pred: wave 0, one node per lane (reads f16 z)
    if (tid < 64) {
        int node = tid;
        float pa = bcs[0], pb = bcs[1], pc = bcs[2];
        for (int k = 0; k < 32; k++) {
            float zv = (float)Zh[node * 40 + k];
            pa += zv * Wcs[k * 4 + 0];
            pb += zv * Wcs[k * 4 + 1];
            pc += zv * Wcs[k * 4 + 2];
        }
        if (row0 + node < n) {
            pred_out[(size_t)(row0 + node) * 3 + 0] = pa;
            pred_out[(size_t)(row0 + node) * 3 + 1] = pb;
            pred_out[(size_t)(row0 + node) * 3 + 2] = pc;
        }
    }
}

// ---------------- GEMM5 (64-row tile): x_recon[n,256] = p2[n,64] @ W_dec_gnn[64,256] + b ---

#define G5_R 64
__global__ __launch_bounds__(256, 3) void k_gemm5(const float* __restrict__ A,
                                                  const float* __restrict__ W,
                                                  const float* __restrict__ bias,
                                                  float* __restrict__ out, int n) {
    __shared__ f16 Wh[64 * 256];      // 32 KB, [k][c]
    __shared__ float As[G5_R * 68];   // 17 KB, padded stride 68
    int tid = threadIdx.x;
    for (int i = tid * 4; i < 64 * 256; i += 1024) {
        float4 w = *(const float4*)&W[i];
        half4 h;
        h.x = (f16)w.x; h.y = (f16)w.y; h.z = (f16)w.z; h.w = (f16)w.w;
        *(half4*)&Wh[i] = h;
    }
    int row0 = blockIdx.x * G5_R;
    for (int j = tid; j < G5_R * 16; j += 256) {
        int r = j >> 4, c4 = (j & 15) * 4;
        int gr = row0 + r;
        float4 v = {0.f, 0.f, 0.f, 0.f};
        if (gr < n) v = *(const float4*)&A[(size_t)gr * 64 + c4];
        *(float4*)&As[r * 68 + c4] = v;
    }
    __syncthreads();

    int cg = (tid & 63) * 4;
    int g  = tid >> 6;
    float acc[16][4];
#pragma unroll
    for (int rr = 0; rr < 16; rr++) {
        acc[rr][0] = 0.f; acc[rr][1] = 0.f; acc[rr][2] = 0.f; acc[rr][3] = 0.f;
    }
    for (int k4 = 0; k4 < 16; k4++) {
        int k = k4 * 4;
        half4 w0 = *(const half4*)&Wh[(k + 0) * 256 + cg];
        half4 w1 = *(const half4*)&Wh[(k + 1) * 256 + cg];
        half4 w2 = *(const half4*)&Wh[(k + 2) * 256 + cg];
        half4 w3 = *(const half4*)&Wh[(k + 3) * 256 + cg];
        float4 f0 = {(float)w0.x, (float)w0.y, (float)w0.z, (float)w0.w};
        float4 f1 = {(float)w1.x, (float)w1.y, (float)w1.z, (float)w1.w};
        float4 f2 = {(float)w2.x, (float)w2.y, (float)w2.z, (float)w2.w};
        float4 f3 = {(float)w3.x, (float)w3.y, (float)w3.z, (float)w3.w};
#pragma unroll
        for (int rr = 0; rr < 16; rr++) {
            int row = g + 4 * rr;
            float4 a = *(const float4*)&As[row * 68 + k];
            acc[rr][0] += a.x * f0.x; acc[rr][1] += a.x * f0.y;
            acc[rr][2] += a.x * f0.z; acc[rr][3] += a.x * f0.w;
            acc[rr][0] += a.y * f1.x; acc[rr][1] += a.y * f1.y;
            acc[rr][2] += a.y * f1.z; acc[rr][3] += a.y * f1.w;
            acc[rr][0] += a.z * f2.x; acc[rr][1] += a.z * f2.y;
            acc[rr][2] += a.z * f2.z; acc[rr][3] += a.z * f2.w;
            acc[rr][0] += a.w * f3.x; acc[rr][1] += a.w * f3.y;
            acc[rr][2] += a.w * f3.z; acc[rr][3] += a.w * f3.w;
        }
    }
    float4 b4 = *(const float4*)&bias[cg];
#pragma unroll
    for (int rr = 0; rr < 16; rr++) {
        int gr = row0 + g + 4 * rr;
        if (gr < n) {
            float4 o;
            o.x = acc[rr][0] + b4.x;
            o.y = acc[rr][1] + b4.y;
            o.z = acc[rr][2] + b4.z;
            o.w = acc[rr][3] + b4.w;
            *(float4*)&out[(size_t)gr * 256 + cg] = o;
        }
    }
}

// ---------------- launch ----------------

extern "C" void kernel_launch(void* const* d_in, const int* in_sizes, int n_in,
                              void* d_out, int out_size, void* d_ws, size_t ws_size,
                              hipStream_t stream) {
    const float* x    = (const float*)d_in[0];
    const int*   ei   = (const int*)d_in[1];
    const float* Wenc = (const float*)d_in[3];
    const float* benc = (const float*)d_in[4];
    const float* Wz   = (const float*)d_in[5];
    const float* bz   = (const float*)d_in[6];
    const float* Wd   = (const float*)d_in[7];
    const float* bd   = (const float*)d_in[8];
    const float* Wdec = (const float*)d_in[9];
    const float* bdec = (const float*)d_in[10];
    const float* Wc   = (const float*)d_in[11];
    const float* bc   = (const float*)d_in[12];

    int n = in_sizes[0] / 256;
    int E = in_sizes[1] / 2;
    const int* src = ei;
    const int* dst = ei + E;

    int nb = (n + 255) / 256;

    char* w = (char*)d_ws;
    size_t off = 0;
    auto alloc = [&](size_t bytes) {
        void* p = w + off;
        off = (off + bytes + 255) & ~(size_t)255;
        return p;
    };
    int*   cnt     = (int*)alloc(sizeof(int) * n);
    int*   row_ptr = (int*)alloc(sizeof(int) * (n + 1));
    int*   cursor  = (int*)alloc(sizeof(int) * n);
    int*   ssorted = (int*)alloc(sizeof(int) * E);
    float* dinv    = (float*)alloc(sizeof(float) * n);
    int*   bsum    = (int*)alloc(sizeof(int) * nb);
    int*   boff    = (int*)alloc(sizeof(int) * nb);
    float* bufA    = (float*)alloc(sizeof(float) * (size_t)n * 64);  // h1pre -> hd
    float* bufB    = (float*)alloc(sizeof(float) * (size_t)n * 64);  // h1 -> p2
    (void)ws_size; (void)n_in; (void)out_size;

    float* out_xr = (float*)d_out;
    float* out_z  = out_xr + (size_t)n * 256;
    float* out_p  = out_z + (size_t)n * 32;

    // CSR build (hierarchical scan)
    k_zero_int<<<dim3(nb), dim3(256), 0, stream>>>(cnt, n);
    k_count<<<dim3((E + 255) / 256), dim3(256), 0, stream>>>(dst, E, cnt);
    k_scan1<<<dim3(nb), dim3(256), 0, stream>>>(cnt, n, bsum);
    k_scan2<<<dim3(1), dim3(256), 0, stream>>>(bsum, nb, boff);
    k_scan3<<<dim3(nb), dim3(256), 0, stream>>>(cnt, n, E, boff, row_ptr, cursor, dinv);
    k_fill<<<dim3((E + 255) / 256), dim3(256), 0, stream>>>(src, dst, E, cursor, ssorted);

    // encoder: bufA = x @ W_enc ; bufB = relu(P bufA + b_enc)
    k_gemm1<<<dim3((n + G1M_R - 1) / G1M_R), dim3(256), 0, stream>>>(x, Wenc, bufA, n);
    k_prop<true><<<dim3((n + 3) / 4), dim3(256), 0, stream>>>(bufA, row_ptr, ssorted, dinv, benc, bufB, n);

    // middle: z (out), pred (out), hd -> bufA
    k_mid<<<dim3((n + MB - 1) / MB), dim3(256), 0, stream>>>(bufB, Wz, bz, Wd, bd, Wc, bc,
                                                             bufA, out_z, out_p, n);

    // decoder (reassociated): bufB = P bufA ; x_recon = bufB @ W_dec + b_dec
    k_prop<false><<<dim3((n + 3) / 4), dim3(256), 0, stream>>>(bufA, row_ptr, ssorted, dinv, benc, bufB, n);
    k_gemm5<<<dim3((n + G5_R - 1) / G5_R), dim3(256), 0, stream>>>(bufB, Wdec, bdec, out_xr, n);
}

// Round 8
// 311.516 us; speedup vs baseline: 2.1583x; 1.1036x over previous
//
#include <hip/hip_runtime.h>
#include <hip/hip_bf16.h>
#include <stdint.h>

typedef _Float16 f16;
typedef _Float16 half4 __attribute__((ext_vector_type(4)));
typedef _Float16 f16x8 __attribute__((ext_vector_type(8)));
typedef float f32x4 __attribute__((ext_vector_type(4)));

// ---------------- CSR build (bucketed counting sort; n <= 131072 assumed for packing) ----

#define BKT_SH 9
#define BKT_SZ 512
#define EB 4096

__global__ void k_zero_int(int* __restrict__ p, int n) {
    int i = blockIdx.x * blockDim.x + threadIdx.x;
    if (i < n) p[i] = 0;
}

// per-chunk LDS histogram of buckets -> global bucket counts
__global__ __launch_bounds__(256) void k_bhist(const int* __restrict__ dst, int E, int nbk,
                                               int* __restrict__ gcnt) {
    __shared__ int h[128];
    int tid = threadIdx.x;
    if (tid < 128) h[tid] = 0;
    __syncthreads();
    int base = blockIdx.x * EB;
    int end = min(base + EB, E);
    for (int i = base + tid; i < end; i += 256) atomicAdd(&h[dst[i] >> BKT_SH], 1);
    __syncthreads();
    if (tid < nbk && h[tid]) atomicAdd(&gcnt[tid], h[tid]);
}

// single block: exclusive scan of bucket counts -> bases + cursors; row_ptr[n] = E
__global__ __launch_bounds__(256) void k_bscan(const int* __restrict__ gcnt, int nbk, int E, int n,
                                               int* __restrict__ bbase, int* __restrict__ bcur,
                                               int* __restrict__ row_ptr) {
    __shared__ int s[256];
    int tid = threadIdx.x;
    int v = (tid < nbk) ? gcnt[tid] : 0;
    s[tid] = v;
    __syncthreads();
    for (int o = 1; o < 256; o <<= 1) {
        int t = (tid >= o) ? s[tid - o] : 0;
        __syncthreads();
        s[tid] += t;
        __syncthreads();
    }
    if (tid < nbk) { bbase[tid] = s[tid] - v; bcur[tid] = s[tid] - v; }
    if (tid == 0) row_ptr[n] = E;
}

// bin edges into bucket-partitioned ebuf; packed = src | (dst_low9 << 17)
__global__ __launch_bounds__(256) void k_binA(const int* __restrict__ src, const int* __restrict__ dst,
                                              int E, int* __restrict__ bcur,
                                              unsigned* __restrict__ ebuf) {
    __shared__ int h[128], segs[128], cur[128];
    int tid = threadIdx.x;
    if (tid < 128) { h[tid] = 0; cur[tid] = 0; }
    __syncthreads();
    int base = blockIdx.x * EB;
    int end = min(base + EB, E);
    for (int i = base + tid; i < end; i += 256) atomicAdd(&h[dst[i] >> BKT_SH], 1);
    __syncthreads();
    if (tid < 128) segs[tid] = h[tid] ? atomicAdd(&bcur[tid], h[tid]) : 0;
    __syncthreads();
    for (int i = base + tid; i < end; i += 256) {
        int d = dst[i];
        int b = d >> BKT_SH;
        int r = atomicAdd(&cur[b], 1);
        ebuf[segs[b] + r] = (unsigned)src[i] | ((unsigned)(d & (BKT_SZ - 1)) << 17);
    }
}

// per-bucket: local count+scan -> row_ptr, dinv, and block-private ssorted scatter
__global__ __launch_bounds__(256) void k_csr(const unsigned* __restrict__ ebuf,
                                             const int* __restrict__ bbase, const int* __restrict__ gcnt,
                                             int n, int* __restrict__ row_ptr,
                                             float* __restrict__ dinv, int* __restrict__ ssorted) {
    __shared__ int cnt[BKT_SZ], exc[BKT_SZ], cur2[BKT_SZ], p[256];
    int b = blockIdx.x, tid = threadIdx.x;
    int d0 = b << BKT_SH;
    int ndl = min(BKT_SZ, n - d0);
    cnt[tid] = 0; cnt[tid + 256] = 0;
    cur2[tid] = 0; cur2[tid + 256] = 0;
    __syncthreads();
    int s0 = bbase[b], scnt = gcnt[b];
    for (int i = tid; i < scnt; i += 256)
        atomicAdd(&cnt[(ebuf[s0 + i] >> 17) & (BKT_SZ - 1)], 1);
    __syncthreads();
    int a = cnt[2 * tid], c2 = cnt[2 * tid + 1];
    p[tid] = a + c2;
    __syncthreads();
    for (int o = 1; o < 256; o <<= 1) {
        int t = (tid >= o) ? p[tid - o] : 0;
        __syncthreads();
        p[tid] += t;
        __syncthreads();
    }
    int pex = p[tid] - (a + c2);
    exc[2 * tid] = pex;
    exc[2 * tid + 1] = pex + a;
    __syncthreads();
    for (int dl = tid; dl < ndl; dl += 256) {
        row_ptr[d0 + dl] = s0 + exc[dl];
        dinv[d0 + dl] = rsqrtf((float)(cnt[dl] + 1));  // +1 self loop
    }
    for (int i = tid; i < scnt; i += 256) {
        unsigned e = ebuf[s0 + i];
        int dl = (e >> 17) & (BKT_SZ - 1);
        int r = atomicAdd(&cur2[dl], 1);
        ssorted[s0 + exc[dl] + r] = (int)(e & 0x1FFFF);
    }
}

// ---------------- GEMM1 (MFMA): h1_pre[n,64] = x[n,256] @ W_enc_gnn[256,64] ----------

#define G1M_R 64
__global__ __launch_bounds__(256) void k_gemm1(const float* __restrict__ x,
                                               const float* __restrict__ W,
                                               float* __restrict__ out, int n) {
    __shared__ __attribute__((aligned(16))) f16 WB[4 * 8 * 64 * 8];  // [t][ks][lane][8] = 32 KB
    __shared__ __attribute__((aligned(16))) f16 Ah[64 * 136];        // [row][k-half], 17 KB
    int tid = threadIdx.x;
    int row0 = blockIdx.x * G1M_R;

    for (int i = tid; i < 4096; i += 256) {
        int k = i >> 4, c4 = (i & 15) * 4;
        float4 w = *(const float4*)&W[k * 64 + c4];
        int t = c4 >> 4, ks = k >> 5, q = (k & 31) >> 3, j = k & 7;
        int base = (((t * 8 + ks) * 64 + q * 16 + (c4 & 15)) * 8) + j;
        WB[base + 0]  = (f16)w.x;
        WB[base + 8]  = (f16)w.y;
        WB[base + 16] = (f16)w.z;
        WB[base + 24] = (f16)w.w;
    }

    int lane = tid & 63, w = tid >> 6;
    int m = lane & 15, q = lane >> 4;

    f32x4 acc[4];
#pragma unroll
    for (int t = 0; t < 4; t++) acc[t] = (f32x4){0.f, 0.f, 0.f, 0.f};

    for (int h = 0; h < 2; h++) {
        __syncthreads();
        for (int i = tid; i < 2048; i += 256) {
            int r = i >> 5, k4 = (i & 31) * 4;
            float4 v = {0.f, 0.f, 0.f, 0.f};
            if (row0 + r < n) v = *(const float4*)&x[(size_t)(row0 + r) * 256 + 128 * h + k4];
            half4 hv;
            hv.x = (f16)v.x; hv.y = (f16)v.y; hv.z = (f16)v.z; hv.w = (f16)v.w;
            *(half4*)&Ah[r * 136 + k4] = hv;
        }
        __syncthreads();
#pragma unroll
        for (int ksl = 0; ksl < 4; ksl++) {
            int ks = 4 * h + ksl;
            f16x8 a = *(const f16x8*)&Ah[(16 * w + m) * 136 + 32 * ksl + 8 * q];
#pragma unroll
            for (int t = 0; t < 4; t++) {
                f16x8 b = *(const f16x8*)&WB[((t * 8 + ks) * 64 + lane) * 8];
                acc[t] = __builtin_amdgcn_mfma_f32_16x16x32_f16(a, b, acc[t], 0, 0, 0);
            }
        }
    }

#pragma unroll
    for (int t = 0; t < 4; t++) {
#pragma unroll
        for (int r = 0; r < 4; r++) {
            int gr = row0 + 16 * w + 4 * q + r;
            if (gr < n) out[(size_t)gr * 64 + 16 * t + m] = acc[t][r];
        }
    }
}

// ---------------- propagation: out[d] = dinv[d]*(sum_s dinv[s]*h[s] + dinv[d]*h[d]) ------

template <bool RELU_BIAS>
__global__ __launch_bounds__(256) void k_prop(const float* __restrict__ hpre,
                                              const int* __restrict__ row_ptr,
                                              const int* __restrict__ ssorted,
                                              const float* __restrict__ dinv,
                                              const float* __restrict__ bias,
                                              float* __restrict__ out, int n) {
    int lane = threadIdx.x & 63, wid = threadIdx.x >> 6;
    int d = blockIdx.x * 4 + wid;
    if (d >= n) return;
    float dd = dinv[d];
    float acc = dd * hpre[(size_t)d * 64 + lane];  // self loop (inner dinv[d])
    int s0 = row_ptr[d], s1 = row_ptr[d + 1];
    for (int base = s0; base < s1; base += 64) {
        int j = base + lane;
        int sl = 0;
        float wl = 0.f;
        if (j < s1) { sl = ssorted[j]; wl = dinv[sl]; }
        int cnt = min(64, s1 - base);
        int i = 0;
        for (; i + 4 <= cnt; i += 4) {
            int a0 = __shfl(sl, i), a1 = __shfl(sl, i + 1);
            int a2 = __shfl(sl, i + 2), a3 = __shfl(sl, i + 3);
            float w0 = __shfl(wl, i), w1 = __shfl(wl, i + 1);
            float w2 = __shfl(wl, i + 2), w3 = __shfl(wl, i + 3);
            float v0 = hpre[(size_t)a0 * 64 + lane];
            float v1 = hpre[(size_t)a1 * 64 + lane];
            float v2 = hpre[(size_t)a2 * 64 + lane];
            float v3 = hpre[(size_t)a3 * 64 + lane];
            acc += w0 * v0; acc += w1 * v1; acc += w2 * v2; acc += w3 * v3;
        }
        for (; i < cnt; i++) {
            int a = __shfl(sl, i);
            float w = __shfl(wl, i);
            acc += w * hpre[(size_t)a * 64 + lane];
        }
    }
    float val = dd * acc;
    if (RELU_BIAS) val = fmaxf(val + bias[lane], 0.f);
    out[(size_t)d * 64 + lane] = val;
}

// ---------------- fused middle (MFMA): 64 nodes per block ----------------

#define MB 64
__global__ __launch_bounds__(256) void k_mid(const float* __restrict__ h1,
                                             const float* __restrict__ Wz, const float* __restrict__ bz,
                                             const float* __restrict__ Wd, const float* __restrict__ bd,
                                             const float* __restrict__ Wc, const float* __restrict__ bc,
                                             float* __restrict__ hd_ws,
                                             float* __restrict__ z_out, float* __restrict__ pred_out,
                                             int n) {
    __shared__ __attribute__((aligned(16))) f16 Ah[64 * 72];
    __shared__ __attribute__((aligned(16))) f16 Zh[64 * 40];
    __shared__ __attribute__((aligned(16))) f16 WzB[2 * 2 * 64 * 8];
    __shared__ __attribute__((aligned(16))) f16 WdB[4 * 64 * 8];
    __shared__ float Wcs[32 * 4];
    __shared__ float bzs[32], bds[64], bcs[4];
    int tid = threadIdx.x;
    int row0 = blockIdx.x * MB;

    for (int i = tid; i < 2048; i += 256) {
        int k = i >> 5, c = i & 31;
        int ks = k >> 5, q = (k >> 3) & 3, j = k & 7;
        int t = c >> 4, ln = q * 16 + (c & 15);
        WzB[((t * 2 + ks) * 64 + ln) * 8 + j] = (f16)Wz[i];
    }
    for (int i = tid; i < 2048; i += 256) {
        int k = i >> 6, c = i & 63;
        int q = k >> 3, j = k & 7;
        int t = c >> 4, ln = q * 16 + (c & 15);
        WdB[(t * 64 + ln) * 8 + j] = (f16)Wd[i];
    }
    if (tid < 96) Wcs[(tid / 3) * 4 + (tid % 3)] = Wc[tid];
    if (tid < 32) bzs[tid] = bz[tid];
    if (tid < 64) bds[tid] = bd[tid];
    if (tid < 3)  bcs[tid] = bc[tid];
    for (int i = tid; i < 1024; i += 256) {
        int r = i >> 4, c4 = (i & 15) * 4;
        float4 v = {0.f, 0.f, 0.f, 0.f};
        if (row0 + r < n) v = *(const float4*)&h1[(size_t)(row0 + r) * 64 + c4];
        half4 hv;
        hv.x = (f16)v.x; hv.y = (f16)v.y; hv.z = (f16)v.z; hv.w = (f16)v.w;
        *(half4*)&Ah[r * 72 + c4] = hv;
    }
    __syncthreads();

    int lane = tid & 63, w = tid >> 6;
    int m = lane & 15, q = lane >> 4;

    f32x4 za[2];
    za[0] = (f32x4){0.f, 0.f, 0.f, 0.f};
    za[1] = (f32x4){0.f, 0.f, 0.f, 0.f};
#pragma unroll
    for (int ks = 0; ks < 2; ks++) {
        f16x8 a = *(const f16x8*)&Ah[(16 * w + m) * 72 + 32 * ks + 8 * q];
#pragma unroll
        for (int t = 0; t < 2; t++) {
            f16x8 b = *(const f16x8*)&WzB[((t * 2 + ks) * 64 + lane) * 8];
            za[t] = __builtin_amdgcn_mfma_f32_16x16x32_f16(a, b, za[t], 0, 0, 0);
        }
    }
#pragma unroll
    for (int t = 0; t < 2; t++) {
        float bj = bzs[16 * t + m];
#pragma unroll
        for (int r = 0; r < 4; r++) {
            int node = 16 * w + 4 * q + r;
            float zv = za[t][r] + bj;
            Zh[node * 40 + 16 * t + m] = (f16)zv;
            if (row0 + node < n) z_out[(size_t)(row0 + node) * 32 + 16 * t + m] = zv;
        }
    }
    __syncthreads();

    f16x8 a2 = *(const f16x8*)&Zh[(16 * w + m) * 40 + 8 * q];
    f32x4 hb[4];
#pragma unroll
    for (int t = 0; t < 4; t++) {
        f16x8 b = *(const f16x8*)&WdB[(t * 64 + lane) * 8];
        f32x4 zero = (f32x4){0.f, 0.f, 0.f, 0.f};
        hb[t] = __builtin_amdgcn_mfma_f32_16x16x32_f16(a2, b, zero, 0, 0, 0);
    }
#pragma unroll
    for (int t = 0; t < 4; t++) {
        float bf = bds[16 * t + m];
#pragma unroll
        for (int r = 0; r < 4; r++) {
            int node = 16 * w + 4 * q + r;
            if (row0 + node < n)
                hd_ws[(size_t)(row0 + node) * 64 + 16 * t + m] = fmaxf(hb[t][r] + bf, 0.f);
        }
    }

    if (tid < 64) {
        int node = tid;
        float pa = bcs[0], pb = bcs[1], pc = bcs[2];
        for (int k = 0; k < 32; k++) {
            float zv = (float)Zh[node * 40 + k];
            pa += zv * Wcs[k * 4 + 0];
            pb += zv * Wcs[k * 4 + 1];
            pc += zv * Wcs[k * 4 + 2];
        }
        if (row0 + node < n) {
            pred_out[(size_t)(row0 + node) * 3 + 0] = pa;
            pred_out[(size_t)(row0 + node) * 3 + 1] = pb;
            pred_out[(size_t)(row0 + node) * 3 + 2] = pc;
        }
    }
}

// ---------------- GEMM5 (64-row tile): x_recon[n,256] = p2[n,64] @ W_dec_gnn[64,256] + b ---

#define G5_R 64
__global__ __launch_bounds__(256, 3) void k_gemm5(const float* __restrict__ A,
                                                  const float* __restrict__ W,
                                                  const float* __restrict__ bias,
                                                  float* __restrict__ out, int n) {
    __shared__ f16 Wh[64 * 256];
    __shared__ float As[G5_R * 68];
    int tid = threadIdx.x;
    for (int i = tid * 4; i < 64 * 256; i += 1024) {
        float4 w = *(const float4*)&W[i];
        half4 h;
        h.x = (f16)w.x; h.y = (f16)w.y; h.z = (f16)w.z; h.w = (f16)w.w;
        *(half4*)&Wh[i] = h;
    }
    int row0 = blockIdx.x * G5_R;
    for (int j = tid; j < G5_R * 16; j += 256) {
        int r = j >> 4, c4 = (j & 15) * 4;
        int gr = row0 + r;
        float4 v = {0.f, 0.f, 0.f, 0.f};
        if (gr < n) v = *(const float4*)&A[(size_t)gr * 64 + c4];
        *(float4*)&As[r * 68 + c4] = v;
    }
    __syncthreads();

    int cg = (tid & 63) * 4;
    int g  = tid >> 6;
    float acc[16][4];
#pragma unroll
    for (int rr = 0; rr < 16; rr++) {
        acc[rr][0] = 0.f; acc[rr][1] = 0.f; acc[rr][2] = 0.f; acc[rr][3] = 0.f;
    }
    for (int k4 = 0; k4 < 16; k4++) {
        int k = k4 * 4;
        half4 w0 = *(const half4*)&Wh[(k + 0) * 256 + cg];
        half4 w1 = *(const half4*)&Wh[(k + 1) * 256 + cg];
        half4 w2 = *(const half4*)&Wh[(k + 2) * 256 + cg];
        half4 w3 = *(const half4*)&Wh[(k + 3) * 256 + cg];
        float4 f0 = {(float)w0.x, (float)w0.y, (float)w0.z, (float)w0.w};
        float4 f1 = {(float)w1.x, (float)w1.y, (float)w1.z, (float)w1.w};
        float4 f2 = {(float)w2.x, (float)w2.y, (float)w2.z, (float)w2.w};
        float4 f3 = {(float)w3.x, (float)w3.y, (float)w3.z, (float)w3.w};
#pragma unroll
        for (int rr = 0; rr < 16; rr++) {
            int row = g + 4 * rr;
            float4 a = *(const float4*)&As[row * 68 + k];
            acc[rr][0] += a.x * f0.x; acc[rr][1] += a.x * f0.y;
            acc[rr][2] += a.x * f0.z; acc[rr][3] += a.x * f0.w;
            acc[rr][0] += a.y * f1.x; acc[rr][1] += a.y * f1.y;
            acc[rr][2] += a.y * f1.z; acc[rr][3] += a.y * f1.w;
            acc[rr][0] += a.z * f2.x; acc[rr][1] += a.z * f2.y;
            acc[rr][2] += a.z * f2.z; acc[rr][3] += a.z * f2.w;
            acc[rr][0] += a.w * f3.x; acc[rr][1] += a.w * f3.y;
            acc[rr][2] += a.w * f3.z; acc[rr][3] += a.w * f3.w;
        }
    }
    float4 b4 = *(const float4*)&bias[cg];
#pragma unroll
    for (int rr = 0; rr < 16; rr++) {
        int gr = row0 + g + 4 * rr;
        if (gr < n) {
            float4 o;
            o.x = acc[rr][0] + b4.x;
            o.y = acc[rr][1] + b4.y;
            o.z = acc[rr][2] + b4.z;
            o.w = acc[rr][3] + b4.w;
            *(float4*)&out[(size_t)gr * 256 + cg] = o;
        }
    }
}

// ---------------- launch ----------------

extern "C" void kernel_launch(void* const* d_in, const int* in_sizes, int n_in,
                              void* d_out, int out_size, void* d_ws, size_t ws_size,
                              hipStream_t stream) {
    const float* x    = (const float*)d_in[0];
    const int*   ei   = (const int*)d_in[1];
    const float* Wenc = (const float*)d_in[3];
    const float* benc = (const float*)d_in[4];
    const float* Wz   = (const float*)d_in[5];
    const float* bz   = (const float*)d_in[6];
    const float* Wd   = (const float*)d_in[7];
    const float* bd   = (const float*)d_in[8];
    const float* Wdec = (const float*)d_in[9];
    const float* bdec = (const float*)d_in[10];
    const float* Wc   = (const float*)d_in[11];
    const float* bc   = (const float*)d_in[12];

    int n = in_sizes[0] / 256;
    int E = in_sizes[1] / 2;
    const int* src = ei;
    const int* dst = ei + E;

    int nbk = (n + BKT_SZ - 1) >> BKT_SH;     // 98 buckets
    int nbin = (E + EB - 1) / EB;             // 196 chunks

    char* w = (char*)d_ws;
    size_t off = 0;
    auto alloc = [&](size_t bytes) {
        void* p = w + off;
        off = (off + bytes + 255) & ~(size_t)255;
        return p;
    };
    int*      row_ptr = (int*)alloc(sizeof(int) * (n + 1));
    int*      ssorted = (int*)alloc(sizeof(int) * E);
    unsigned* ebuf    = (unsigned*)alloc(sizeof(unsigned) * E);
    float*    dinv    = (float*)alloc(sizeof(float) * n);
    int*      gcnt    = (int*)alloc(sizeof(int) * 128);
    int*      bbase   = (int*)alloc(sizeof(int) * 128);
    int*      bcur    = (int*)alloc(sizeof(int) * 128);
    float*    bufA    = (float*)alloc(sizeof(float) * (size_t)n * 64);  // h1pre -> hd
    float*    bufB    = (float*)alloc(sizeof(float) * (size_t)n * 64);  // h1 -> p2
    (void)ws_size; (void)n_in; (void)out_size;

    float* out_xr = (float*)d_out;
    float* out_z  = out_xr + (size_t)n * 256;
    float* out_p  = out_z + (size_t)n * 32;

    // CSR build (bucketed counting sort)
    k_zero_int<<<dim3(1), dim3(128), 0, stream>>>(gcnt, 128);
    k_bhist<<<dim3(nbin), dim3(256), 0, stream>>>(dst, E, nbk, gcnt);
    k_bscan<<<dim3(1), dim3(256), 0, stream>>>(gcnt, nbk, E, n, bbase, bcur, row_ptr);
    k_binA<<<dim3(nbin), dim3(256), 0, stream>>>(src, dst, E, bcur, ebuf);
    k_csr<<<dim3(nbk), dim3(256), 0, stream>>>(ebuf, bbase, gcnt, n, row_ptr, dinv, ssorted);

    // encoder: bufA = x @ W_enc ; bufB = relu(P bufA + b_enc)
    k_gemm1<<<dim3((n + G1M_R - 1) / G1M_R), dim3(256), 0, stream>>>(x, Wenc, bufA, n);
    k_prop<true><<<dim3((n + 3) / 4), dim3(256), 0, stream>>>(bufA, row_ptr, ssorted, dinv, benc, bufB, n);

    // middle: z (out), pred (out), hd -> bufA
    k_mid<<<dim3((n + MB - 1) / MB), dim3(256), 0, stream>>>(bufB, Wz, bz, Wd, bd, Wc, bc,
                                                             bufA, out_z, out_p, n);

    // decoder (reassociated): bufB = P bufA ; x_recon = bufB @ W_dec + b_dec
    k_prop<false><<<dim3((n + 3) / 4), dim3(256), 0, stream>>>(bufA, row_ptr, ssorted, dinv, benc, bufB, n);
    k_gemm5<<<dim3((n + G5_R - 1) / G5_R), dim3(256), 0, stream>>>(bufB, Wdec, bdec, out_xr, n);
}

// Round 9
// 291.989 us; speedup vs baseline: 2.3027x; 1.0669x over previous
//
#include <hip/hip_runtime.h>
#include <hip/hip_bf16.h>
#include <stdint.h>

typedef _Float16 f16;
typedef _Float16 half4 __attribute__((ext_vector_type(4)));
typedef _Float16 f16x8 __attribute__((ext_vector_type(8)));
typedef float f32x4 __attribute__((ext_vector_type(4)));

// ---------------- CSR build (bucketed counting sort; n <= 131072 assumed for packing) ----

#define BKT_SH 9
#define BKT_SZ 512
#define EB 4096

__global__ void k_zero_int(int* __restrict__ p, int n) {
    int i = blockIdx.x * blockDim.x + threadIdx.x;
    if (i < n) p[i] = 0;
}

// per-chunk LDS histogram of buckets -> global bucket counts
__global__ __launch_bounds__(256) void k_bhist(const int* __restrict__ dst, int E, int nbk,
                                               int* __restrict__ gcnt) {
    __shared__ int h[128];
    int tid = threadIdx.x;
    if (tid < 128) h[tid] = 0;
    __syncthreads();
    int base = blockIdx.x * EB;
    int end = min(base + EB, E);
    for (int i = base + tid; i < end; i += 256) atomicAdd(&h[dst[i] >> BKT_SH], 1);
    __syncthreads();
    if (tid < nbk && h[tid]) atomicAdd(&gcnt[tid], h[tid]);
}

// single block: exclusive scan of bucket counts -> bases + cursors; row_ptr[n] = E
__global__ __launch_bounds__(256) void k_bscan(const int* __restrict__ gcnt, int nbk, int E, int n,
                                               int* __restrict__ bbase, int* __restrict__ bcur,
                                               int* __restrict__ row_ptr) {
    __shared__ int s[256];
    int tid = threadIdx.x;
    int v = (tid < nbk) ? gcnt[tid] : 0;
    s[tid] = v;
    __syncthreads();
    for (int o = 1; o < 256; o <<= 1) {
        int t = (tid >= o) ? s[tid - o] : 0;
        __syncthreads();
        s[tid] += t;
        __syncthreads();
    }
    if (tid < nbk) { bbase[tid] = s[tid] - v; bcur[tid] = s[tid] - v; }
    if (tid == 0) row_ptr[n] = E;
}

// bin edges into bucket-partitioned ebuf; packed = src | (dst_low9 << 17)
__global__ __launch_bounds__(256) void k_binA(const int* __restrict__ src, const int* __restrict__ dst,
                                              int E, int* __restrict__ bcur,
                                              unsigned* __restrict__ ebuf) {
    __shared__ int h[128], segs[128], cur[128];
    int tid = threadIdx.x;
    if (tid < 128) { h[tid] = 0; cur[tid] = 0; }
    __syncthreads();
    int base = blockIdx.x * EB;
    int end = min(base + EB, E);
    for (int i = base + tid; i < end; i += 256) atomicAdd(&h[dst[i] >> BKT_SH], 1);
    __syncthreads();
    if (tid < 128) segs[tid] = h[tid] ? atomicAdd(&bcur[tid], h[tid]) : 0;
    __syncthreads();
    for (int i = base + tid; i < end; i += 256) {
        int d = dst[i];
        int b = d >> BKT_SH;
        int r = atomicAdd(&cur[b], 1);
        ebuf[segs[b] + r] = (unsigned)src[i] | ((unsigned)(d & (BKT_SZ - 1)) << 17);
    }
}

// per-bucket: local count+scan -> row_ptr, dinv, and block-private ssorted scatter
__global__ __launch_bounds__(256) void k_csr(const unsigned* __restrict__ ebuf,
                                             const int* __restrict__ bbase, const int* __restrict__ gcnt,
                                             int n, int* __restrict__ row_ptr,
                                             float* __restrict__ dinv, int* __restrict__ ssorted) {
    __shared__ int cnt[BKT_SZ], exc[BKT_SZ], cur2[BKT_SZ], p[256];
    int b = blockIdx.x, tid = threadIdx.x;
    int d0 = b << BKT_SH;
    int ndl = min(BKT_SZ, n - d0);
    cnt[tid] = 0; cnt[tid + 256] = 0;
    cur2[tid] = 0; cur2[tid + 256] = 0;
    __syncthreads();
    int s0 = bbase[b], scnt = gcnt[b];
    for (int i = tid; i < scnt; i += 256)
        atomicAdd(&cnt[(ebuf[s0 + i] >> 17) & (BKT_SZ - 1)], 1);
    __syncthreads();
    int a = cnt[2 * tid], c2 = cnt[2 * tid + 1];
    p[tid] = a + c2;
    __syncthreads();
    for (int o = 1; o < 256; o <<= 1) {
        int t = (tid >= o) ? p[tid - o] : 0;
        __syncthreads();
        p[tid] += t;
        __syncthreads();
    }
    int pex = p[tid] - (a + c2);
    exc[2 * tid] = pex;
    exc[2 * tid + 1] = pex + a;
    __syncthreads();
    for (int dl = tid; dl < ndl; dl += 256) {
        row_ptr[d0 + dl] = s0 + exc[dl];
        dinv[d0 + dl] = rsqrtf((float)(cnt[dl] + 1));  // +1 self loop
    }
    for (int i = tid; i < scnt; i += 256) {
        unsigned e = ebuf[s0 + i];
        int dl = (e >> 17) & (BKT_SZ - 1);
        int r = atomicAdd(&cur2[dl], 1);
        ssorted[s0 + exc[dl] + r] = (int)(e & 0x1FFFF);
    }
}

// ---------------- GEMM1 (MFMA): h1_pre[n,64] = x[n,256] @ W_enc_gnn[256,64] ----------

#define G1M_R 64
__global__ __launch_bounds__(256) void k_gemm1(const float* __restrict__ x,
                                               const float* __restrict__ W,
                                               float* __restrict__ out, int n) {
    __shared__ __attribute__((aligned(16))) f16 WB[4 * 8 * 64 * 8];  // [t][ks][lane][8] = 32 KB
    __shared__ __attribute__((aligned(16))) f16 Ah[64 * 136];        // [row][k-half], 17 KB
    int tid = threadIdx.x;
    int row0 = blockIdx.x * G1M_R;

    for (int i = tid; i < 4096; i += 256) {
        int k = i >> 4, c4 = (i & 15) * 4;
        float4 w = *(const float4*)&W[k * 64 + c4];
        int t = c4 >> 4, ks = k >> 5, q = (k & 31) >> 3, j = k & 7;
        int base = (((t * 8 + ks) * 64 + q * 16 + (c4 & 15)) * 8) + j;
        WB[base + 0]  = (f16)w.x;
        WB[base + 8]  = (f16)w.y;
        WB[base + 16] = (f16)w.z;
        WB[base + 24] = (f16)w.w;
    }

    int lane = tid & 63, w = tid >> 6;
    int m = lane & 15, q = lane >> 4;

    f32x4 acc[4];
#pragma unroll
    for (int t = 0; t < 4; t++) acc[t] = (f32x4){0.f, 0.f, 0.f, 0.f};

    for (int h = 0; h < 2; h++) {
        __syncthreads();
        for (int i = tid; i < 2048; i += 256) {
            int r = i >> 5, k4 = (i & 31) * 4;
            float4 v = {0.f, 0.f, 0.f, 0.f};
            if (row0 + r < n) v = *(const float4*)&x[(size_t)(row0 + r) * 256 + 128 * h + k4];
            half4 hv;
            hv.x = (f16)v.x; hv.y = (f16)v.y; hv.z = (f16)v.z; hv.w = (f16)v.w;
            *(half4*)&Ah[r * 136 + k4] = hv;
        }
        __syncthreads();
#pragma unroll
        for (int ksl = 0; ksl < 4; ksl++) {
            int ks = 4 * h + ksl;
            f16x8 a = *(const f16x8*)&Ah[(16 * w + m) * 136 + 32 * ksl + 8 * q];
#pragma unroll
            for (int t = 0; t < 4; t++) {
                f16x8 b = *(const f16x8*)&WB[((t * 8 + ks) * 64 + lane) * 8];
                acc[t] = __builtin_amdgcn_mfma_f32_16x16x32_f16(a, b, acc[t], 0, 0, 0);
            }
        }
    }

#pragma unroll
    for (int t = 0; t < 4; t++) {
#pragma unroll
        for (int r = 0; r < 4; r++) {
            int gr = row0 + 16 * w + 4 * q + r;
            if (gr < n) out[(size_t)gr * 64 + 16 * t + m] = acc[t][r];
        }
    }
}

// ---------------- propagation: out[d] = dinv[d]*(sum_s dinv[s]*h[s] + dinv[d]*h[d]) ------

template <bool RELU_BIAS>
__global__ __launch_bounds__(256) void k_prop(const float* __restrict__ hpre,
                                              const int* __restrict__ row_ptr,
                                              const int* __restrict__ ssorted,
                                              const float* __restrict__ dinv,
                                              const float* __restrict__ bias,
                                              float* __restrict__ out, int n) {
    int lane = threadIdx.x & 63, wid = threadIdx.x >> 6;
    int d = blockIdx.x * 4 + wid;
    if (d >= n) return;
    float dd = dinv[d];
    float acc = dd * hpre[(size_t)d * 64 + lane];  // self loop (inner dinv[d])
    int s0 = row_ptr[d], s1 = row_ptr[d + 1];
    for (int base = s0; base < s1; base += 64) {
        int j = base + lane;
        int sl = 0;
        float wl = 0.f;
        if (j < s1) { sl = ssorted[j]; wl = dinv[sl]; }
        int cnt = min(64, s1 - base);
        int i = 0;
        for (; i + 4 <= cnt; i += 4) {
            int a0 = __shfl(sl, i), a1 = __shfl(sl, i + 1);
            int a2 = __shfl(sl, i + 2), a3 = __shfl(sl, i + 3);
            float w0 = __shfl(wl, i), w1 = __shfl(wl, i + 1);
            float w2 = __shfl(wl, i + 2), w3 = __shfl(wl, i + 3);
            float v0 = hpre[(size_t)a0 * 64 + lane];
            float v1 = hpre[(size_t)a1 * 64 + lane];
            float v2 = hpre[(size_t)a2 * 64 + lane];
            float v3 = hpre[(size_t)a3 * 64 + lane];
            acc += w0 * v0; acc += w1 * v1; acc += w2 * v2; acc += w3 * v3;
        }
        for (; i < cnt; i++) {
            int a = __shfl(sl, i);
            float w = __shfl(wl, i);
            acc += w * hpre[(size_t)a * 64 + lane];
        }
    }
    float val = dd * acc;
    if (RELU_BIAS) val = fmaxf(val + bias[lane], 0.f);
    out[(size_t)d * 64 + lane] = val;
}

// ---------------- fused middle (MFMA): 64 nodes per block ----------------

#define MB 64
__global__ __launch_bounds__(256) void k_mid(const float* __restrict__ h1,
                                             const float* __restrict__ Wz, const float* __restrict__ bz,
                                             const float* __restrict__ Wd, const float* __restrict__ bd,
                                             const float* __restrict__ Wc, const float* __restrict__ bc,
                                             float* __restrict__ hd_ws,
                                             float* __restrict__ z_out, float* __restrict__ pred_out,
                                             int n) {
    __shared__ __attribute__((aligned(16))) f16 Ah[64 * 72];
    __shared__ __attribute__((aligned(16))) f16 Zh[64 * 40];
    __shared__ __attribute__((aligned(16))) f16 WzB[2 * 2 * 64 * 8];
    __shared__ __attribute__((aligned(16))) f16 WdB[4 * 64 * 8];
    __shared__ float Wcs[32 * 4];
    __shared__ float bzs[32], bds[64], bcs[4];
    int tid = threadIdx.x;
    int row0 = blockIdx.x * MB;

    for (int i = tid; i < 2048; i += 256) {
        int k = i >> 5, c = i & 31;
        int ks = k >> 5, q = (k >> 3) & 3, j = k & 7;
        int t = c >> 4, ln = q * 16 + (c & 15);
        WzB[((t * 2 + ks) * 64 + ln) * 8 + j] = (f16)Wz[i];
    }
    for (int i = tid; i < 2048; i += 256) {
        int k = i >> 6, c = i & 63;
        int q = k >> 3, j = k & 7;
        int t = c >> 4, ln = q * 16 + (c & 15);
        WdB[(t * 64 + ln) * 8 + j] = (f16)Wd[i];
    }
    if (tid < 96) Wcs[(tid / 3) * 4 + (tid % 3)] = Wc[tid];
    if (tid < 32) bzs[tid] = bz[tid];
    if (tid < 64) bds[tid] = bd[tid];
    if (tid < 3)  bcs[tid] = bc[tid];
    for (int i = tid; i < 1024; i += 256) {
        int r = i >> 4, c4 = (i & 15) * 4;
        float4 v = {0.f, 0.f, 0.f, 0.f};
        if (row0 + r < n) v = *(const float4*)&h1[(size_t)(row0 + r) * 64 + c4];
        half4 hv;
        hv.x = (f16)v.x; hv.y = (f16)v.y; hv.z = (f16)v.z; hv.w = (f16)v.w;
        *(half4*)&Ah[r * 72 + c4] = hv;
    }
    __syncthreads();

    int lane = tid & 63, w = tid >> 6;
    int m = lane & 15, q = lane >> 4;

    f32x4 za[2];
    za[0] = (f32x4){0.f, 0.f, 0.f, 0.f};
    za[1] = (f32x4){0.f, 0.f, 0.f, 0.f};
#pragma unroll
    for (int ks = 0; ks < 2; ks++) {
        f16x8 a = *(const f16x8*)&Ah[(16 * w + m) * 72 + 32 * ks + 8 * q];
#pragma unroll
        for (int t = 0; t < 2; t++) {
            f16x8 b = *(const f16x8*)&WzB[((t * 2 + ks) * 64 + lane) * 8];
            za[t] = __builtin_amdgcn_mfma_f32_16x16x32_f16(a, b, za[t], 0, 0, 0);
        }
    }
#pragma unroll
    for (int t = 0; t < 2; t++) {
        float bj = bzs[16 * t + m];
#pragma unroll
        for (int r = 0; r < 4; r++) {
            int node = 16 * w + 4 * q + r;
            float zv = za[t][r] + bj;
            Zh[node * 40 + 16 * t + m] = (f16)zv;
            if (row0 + node < n) z_out[(size_t)(row0 + node) * 32 + 16 * t + m] = zv;
        }
    }
    __syncthreads();

    f16x8 a2 = *(const f16x8*)&Zh[(16 * w + m) * 40 + 8 * q];
    f32x4 hb[4];
#pragma unroll
    for (int t = 0; t < 4; t++) {
        f16x8 b = *(const f16x8*)&WdB[(t * 64 + lane) * 8];
        f32x4 zero = (f32x4){0.f, 0.f, 0.f, 0.f};
        hb[t] = __builtin_amdgcn_mfma_f32_16x16x32_f16(a2, b, zero, 0, 0, 0);
    }
#pragma unroll
    for (int t = 0; t < 4; t++) {
        float bf = bds[16 * t + m];
#pragma unroll
        for (int r = 0; r < 4; r++) {
            int node = 16 * w + 4 * q + r;
            if (row0 + node < n)
                hd_ws[(size_t)(row0 + node) * 64 + 16 * t + m] = fmaxf(hb[t][r] + bf, 0.f);
        }
    }

    if (tid < 64) {
        int node = tid;
        float pa = bcs[0], pb = bcs[1], pc = bcs[2];
        for (int k = 0; k < 32; k++) {
            float zv = (float)Zh[node * 40 + k];
            pa += zv * Wcs[k * 4 + 0];
            pb += zv * Wcs[k * 4 + 1];
            pc += zv * Wcs[k * 4 + 2];
        }
        if (row0 + node < n) {
            pred_out[(size_t)(row0 + node) * 3 + 0] = pa;
            pred_out[(size_t)(row0 + node) * 3 + 1] = pb;
            pred_out[(size_t)(row0 + node) * 3 + 2] = pc;
        }
    }
}

// ---------------- GEMM5 (MFMA): x_recon[n,256] = p2[n,64] @ W_dec_gnn[64,256] + b ---------
// 64-row tile; K=64 = 2 MFMA k-steps; 16 col-tiles streamed with one live accumulator.
// Same verified fragment layouts as k_gemm1/k_mid.

#define G5_R 64
__global__ __launch_bounds__(256) void k_gemm5(const float* __restrict__ A,
                                               const float* __restrict__ W,
                                               const float* __restrict__ bias,
                                               float* __restrict__ out, int n) {
    __shared__ __attribute__((aligned(16))) f16 WB[16 * 2 * 64 * 8];  // [(t*2+ks)][lane][j] = 32 KB
    __shared__ __attribute__((aligned(16))) f16 Ah[64 * 72];          // 9 KB
    __shared__ float bs[256];
    int tid = threadIdx.x;
    int row0 = blockIdx.x * G5_R;

    // stage W [64k x 256c] -> B-frag order (float4 coalesced reads)
    for (int i = tid; i < 4096; i += 256) {
        int k = i >> 6, c4 = (i & 63) * 4;
        float4 w = *(const float4*)&W[k * 256 + c4];
        int ks = k >> 5, q = (k >> 3) & 3, j = k & 7;
        int t = c4 >> 4;
        int base = ((t * 2 + ks) * 64 + q * 16 + (c4 & 15)) * 8 + j;
        WB[base + 0]  = (f16)w.x;
        WB[base + 8]  = (f16)w.y;
        WB[base + 16] = (f16)w.z;
        WB[base + 24] = (f16)w.w;
    }
    // stage A tile -> f16
    for (int i = tid; i < 1024; i += 256) {
        int r = i >> 4, c4 = (i & 15) * 4;
        float4 v = {0.f, 0.f, 0.f, 0.f};
        if (row0 + r < n) v = *(const float4*)&A[(size_t)(row0 + r) * 64 + c4];
        half4 hv;
        hv.x = (f16)v.x; hv.y = (f16)v.y; hv.z = (f16)v.z; hv.w = (f16)v.w;
        *(half4*)&Ah[r * 72 + c4] = hv;
    }
    bs[tid] = bias[tid];
    __syncthreads();

    int lane = tid & 63, w = tid >> 6;
    int m = lane & 15, q = lane >> 4;

    f16x8 a0 = *(const f16x8*)&Ah[(16 * w + m) * 72 + 0 + 8 * q];
    f16x8 a1 = *(const f16x8*)&Ah[(16 * w + m) * 72 + 32 + 8 * q];

    int gr0 = row0 + 16 * w + 4 * q;
    bool full = (gr0 + 3 < n);
#pragma unroll 4
    for (int t = 0; t < 16; t++) {
        f32x4 acc = (f32x4){0.f, 0.f, 0.f, 0.f};
        f16x8 b0 = *(const f16x8*)&WB[((t * 2 + 0) * 64 + lane) * 8];
        acc = __builtin_amdgcn_mfma_f32_16x16x32_f16(a0, b0, acc, 0, 0, 0);
        f16x8 b1 = *(const f16x8*)&WB[((t * 2 + 1) * 64 + lane) * 8];
        acc = __builtin_amdgcn_mfma_f32_16x16x32_f16(a1, b1, acc, 0, 0, 0);
        float bf = bs[16 * t + m];
        if (full) {
#pragma unroll
            for (int r = 0; r < 4; r++)
                out[(size_t)(gr0 + r) * 256 + 16 * t + m] = acc[r] + bf;
        } else {
#pragma unroll
            for (int r = 0; r < 4; r++)
                if (gr0 + r < n) out[(size_t)(gr0 + r) * 256 + 16 * t + m] = acc[r] + bf;
        }
    }
}

// ---------------- launch ----------------

extern "C" void kernel_launch(void* const* d_in, const int* in_sizes, int n_in,
                              void* d_out, int out_size, void* d_ws, size_t ws_size,
                              hipStream_t stream) {
    const float* x    = (const float*)d_in[0];
    const int*   ei   = (const int*)d_in[1];
    const float* Wenc = (const float*)d_in[3];
    const float* benc = (const float*)d_in[4];
    const float* Wz   = (const float*)d_in[5];
    const float* bz   = (const float*)d_in[6];
    const float* Wd   = (const float*)d_in[7];
    const float* bd   = (const float*)d_in[8];
    const float* Wdec = (const float*)d_in[9];
    const float* bdec = (const float*)d_in[10];
    const float* Wc   = (const float*)d_in[11];
    const float* bc   = (const float*)d_in[12];

    int n = in_sizes[0] / 256;
    int E = in_sizes[1] / 2;
    const int* src = ei;
    const int* dst = ei + E;

    int nbk = (n + BKT_SZ - 1) >> BKT_SH;     // 98 buckets
    int nbin = (E + EB - 1) / EB;             // 196 chunks

    char* w = (char*)d_ws;
    size_t off = 0;
    auto alloc = [&](size_t bytes) {
        void* p = w + off;
        off = (off + bytes + 255) & ~(size_t)255;
        return p;
    };
    int*      row_ptr = (int*)alloc(sizeof(int) * (n + 1));
    int*      ssorted = (int*)alloc(sizeof(int) * E);
    unsigned* ebuf    = (unsigned*)alloc(sizeof(unsigned) * E);
    float*    dinv    = (float*)alloc(sizeof(float) * n);
    int*      gcnt    = (int*)alloc(sizeof(int) * 128);
    int*      bbase   = (int*)alloc(sizeof(int) * 128);
    int*      bcur    = (int*)alloc(sizeof(int) * 128);
    float*    bufA    = (float*)alloc(sizeof(float) * (size_t)n * 64);  // h1pre -> hd
    float*    bufB    = (float*)alloc(sizeof(float) * (size_t)n * 64);  // h1 -> p2
    (void)ws_size; (void)n_in; (void)out_size;

    float* out_xr = (float*)d_out;
    float* out_z  = out_xr + (size_t)n * 256;
    float* out_p  = out_z + (size_t)n * 32;

    // CSR build (bucketed counting sort)
    k_zero_int<<<dim3(1), dim3(128), 0, stream>>>(gcnt, 128);
    k_bhist<<<dim3(nbin), dim3(256), 0, stream>>>(dst, E, nbk, gcnt);
    k_bscan<<<dim3(1), dim3(256), 0, stream>>>(gcnt, nbk, E, n, bbase, bcur, row_ptr);
    k_binA<<<dim3(nbin), dim3(256), 0, stream>>>(src, dst, E, bcur, ebuf);
    k_csr<<<dim3(nbk), dim3(256), 0, stream>>>(ebuf, bbase, gcnt, n, row_ptr, dinv, ssorted);

    // encoder: bufA = x @ W_enc ; bufB = relu(P bufA + b_enc)
    k_gemm1<<<dim3((n + G1M_R - 1) / G1M_R), dim3(256), 0, stream>>>(x, Wenc, bufA, n);
    k_prop<true><<<dim3((n + 3) / 4), dim3(256), 0, stream>>>(bufA, row_ptr, ssorted, dinv, benc, bufB, n);

    // middle: z (out), pred (out), hd -> bufA
    k_mid<<<dim3((n + MB - 1) / MB), dim3(256), 0, stream>>>(bufB, Wz, bz, Wd, bd, Wc, bc,
                                                             bufA, out_z, out_p, n);

    // decoder (reassociated): bufB = P bufA ; x_recon = bufB @ W_dec + b_dec
    k_prop<false><<<dim3((n + 3) / 4), dim3(256), 0, stream>>>(bufA, row_ptr, ssorted, dinv, benc, bufB, n);
    k_gemm5<<<dim3((n + G5_R - 1) / G5_R), dim3(256), 0, stream>>>(bufB, Wdec, bdec, out_xr, n);
}

// Round 10
// 281.379 us; speedup vs baseline: 2.3895x; 1.0377x over previous
//
#include <hip/hip_runtime.h>
#include <hip/hip_bf16.h>
#include <stdint.h>

typedef _Float16 f16;
typedef _Float16 half4 __attribute__((ext_vector_type(4)));
typedef _Float16 f16x8 __attribute__((ext_vector_type(8)));
typedef float f32x4 __attribute__((ext_vector_type(4)));

// ---------------- CSR build (bucketed counting sort; n <= 131072 assumed for packing) ----

#define BKT_SH 9
#define BKT_SZ 512
#define EB 4096

__global__ void k_zero_int(int* __restrict__ p, int n) {
    int i = blockIdx.x * blockDim.x + threadIdx.x;
    if (i < n) p[i] = 0;
}

__global__ __launch_bounds__(256) void k_bhist(const int* __restrict__ dst, int E, int nbk,
                                               int* __restrict__ gcnt) {
    __shared__ int h[128];
    int tid = threadIdx.x;
    if (tid < 128) h[tid] = 0;
    __syncthreads();
    int base = blockIdx.x * EB;
    int end = min(base + EB, E);
    for (int i = base + tid; i < end; i += 256) atomicAdd(&h[dst[i] >> BKT_SH], 1);
    __syncthreads();
    if (tid < nbk && h[tid]) atomicAdd(&gcnt[tid], h[tid]);
}

__global__ __launch_bounds__(256) void k_bscan(const int* __restrict__ gcnt, int nbk, int E, int n,
                                               int* __restrict__ bbase, int* __restrict__ bcur,
                                               int* __restrict__ row_ptr) {
    __shared__ int s[256];
    int tid = threadIdx.x;
    int v = (tid < nbk) ? gcnt[tid] : 0;
    s[tid] = v;
    __syncthreads();
    for (int o = 1; o < 256; o <<= 1) {
        int t = (tid >= o) ? s[tid - o] : 0;
        __syncthreads();
        s[tid] += t;
        __syncthreads();
    }
    if (tid < nbk) { bbase[tid] = s[tid] - v; bcur[tid] = s[tid] - v; }
    if (tid == 0) row_ptr[n] = E;
}

__global__ __launch_bounds__(256) void k_binA(const int* __restrict__ src, const int* __restrict__ dst,
                                              int E, int* __restrict__ bcur,
                                              unsigned* __restrict__ ebuf) {
    __shared__ int h[128], segs[128], cur[128];
    int tid = threadIdx.x;
    if (tid < 128) { h[tid] = 0; cur[tid] = 0; }
    __syncthreads();
    int base = blockIdx.x * EB;
    int end = min(base + EB, E);
    for (int i = base + tid; i < end; i += 256) atomicAdd(&h[dst[i] >> BKT_SH], 1);
    __syncthreads();
    if (tid < 128) segs[tid] = h[tid] ? atomicAdd(&bcur[tid], h[tid]) : 0;
    __syncthreads();
    for (int i = base + tid; i < end; i += 256) {
        int d = dst[i];
        int b = d >> BKT_SH;
        int r = atomicAdd(&cur[b], 1);
        ebuf[segs[b] + r] = (unsigned)src[i] | ((unsigned)(d & (BKT_SZ - 1)) << 17);
    }
}

__global__ __launch_bounds__(256) void k_csr(const unsigned* __restrict__ ebuf,
                                             const int* __restrict__ bbase, const int* __restrict__ gcnt,
                                             int n, int* __restrict__ row_ptr,
                                             float* __restrict__ dinv, int* __restrict__ ssorted) {
    __shared__ int cnt[BKT_SZ], exc[BKT_SZ], cur2[BKT_SZ], p[256];
    int b = blockIdx.x, tid = threadIdx.x;
    int d0 = b << BKT_SH;
    int ndl = min(BKT_SZ, n - d0);
    cnt[tid] = 0; cnt[tid + 256] = 0;
    cur2[tid] = 0; cur2[tid + 256] = 0;
    __syncthreads();
    int s0 = bbase[b], scnt = gcnt[b];
    for (int i = tid; i < scnt; i += 256)
        atomicAdd(&cnt[(ebuf[s0 + i] >> 17) & (BKT_SZ - 1)], 1);
    __syncthreads();
    int a = cnt[2 * tid], c2 = cnt[2 * tid + 1];
    p[tid] = a + c2;
    __syncthreads();
    for (int o = 1; o < 256; o <<= 1) {
        int t = (tid >= o) ? p[tid - o] : 0;
        __syncthreads();
        p[tid] += t;
        __syncthreads();
    }
    int pex = p[tid] - (a + c2);
    exc[2 * tid] = pex;
    exc[2 * tid + 1] = pex + a;
    __syncthreads();
    for (int dl = tid; dl < ndl; dl += 256) {
        row_ptr[d0 + dl] = s0 + exc[dl];
        dinv[d0 + dl] = rsqrtf((float)(cnt[dl] + 1));  // +1 self loop
    }
    for (int i = tid; i < scnt; i += 256) {
        unsigned e = ebuf[s0 + i];
        int dl = (e >> 17) & (BKT_SZ - 1);
        int r = atomicAdd(&cur2[dl], 1);
        ssorted[s0 + exc[dl] + r] = (int)(e & 0x1FFFF);
    }
}

// ---------------- GEMM1 (MFMA): h1_pre[n,64] = x[n,256] @ W_enc_gnn[256,64] -> f16 ------

#define G1M_R 64
__global__ __launch_bounds__(256) void k_gemm1(const float* __restrict__ x,
                                               const float* __restrict__ W,
                                               f16* __restrict__ out, int n) {
    __shared__ __attribute__((aligned(16))) f16 WB[4 * 8 * 64 * 8];  // 32 KB
    __shared__ __attribute__((aligned(16))) f16 Ah[64 * 136];        // 17 KB
    int tid = threadIdx.x;
    int row0 = blockIdx.x * G1M_R;

    for (int i = tid; i < 4096; i += 256) {
        int k = i >> 4, c4 = (i & 15) * 4;
        float4 w = *(const float4*)&W[k * 64 + c4];
        int t = c4 >> 4, ks = k >> 5, q = (k & 31) >> 3, j = k & 7;
        int base = (((t * 8 + ks) * 64 + q * 16 + (c4 & 15)) * 8) + j;
        WB[base + 0]  = (f16)w.x;
        WB[base + 8]  = (f16)w.y;
        WB[base + 16] = (f16)w.z;
        WB[base + 24] = (f16)w.w;
    }

    int lane = tid & 63, w = tid >> 6;
    int m = lane & 15, q = lane >> 4;

    f32x4 acc[4];
#pragma unroll
    for (int t = 0; t < 4; t++) acc[t] = (f32x4){0.f, 0.f, 0.f, 0.f};

    for (int h = 0; h < 2; h++) {
        __syncthreads();
        for (int i = tid; i < 2048; i += 256) {
            int r = i >> 5, k4 = (i & 31) * 4;
            float4 v = {0.f, 0.f, 0.f, 0.f};
            if (row0 + r < n) v = *(const float4*)&x[(size_t)(row0 + r) * 256 + 128 * h + k4];
            half4 hv;
            hv.x = (f16)v.x; hv.y = (f16)v.y; hv.z = (f16)v.z; hv.w = (f16)v.w;
            *(half4*)&Ah[r * 136 + k4] = hv;
        }
        __syncthreads();
#pragma unroll
        for (int ksl = 0; ksl < 4; ksl++) {
            int ks = 4 * h + ksl;
            f16x8 a = *(const f16x8*)&Ah[(16 * w + m) * 136 + 32 * ksl + 8 * q];
#pragma unroll
            for (int t = 0; t < 4; t++) {
                f16x8 b = *(const f16x8*)&WB[((t * 8 + ks) * 64 + lane) * 8];
                acc[t] = __builtin_amdgcn_mfma_f32_16x16x32_f16(a, b, acc[t], 0, 0, 0);
            }
        }
    }

#pragma unroll
    for (int t = 0; t < 4; t++) {
#pragma unroll
        for (int r = 0; r < 4; r++) {
            int gr = row0 + 16 * w + 4 * q + r;
            if (gr < n) out[(size_t)gr * 64 + 16 * t + m] = (f16)acc[t][r];
        }
    }
}

// ---------------- propagation (f16 in/out): out[d] = dinv[d]*(sum dinv[s]*h[s] + dinv[d]*h[d])

template <bool RELU_BIAS>
__global__ __launch_bounds__(256) void k_prop(const f16* __restrict__ hpre,
                                              const int* __restrict__ row_ptr,
                                              const int* __restrict__ ssorted,
                                              const float* __restrict__ dinv,
                                              const float* __restrict__ bias,
                                              f16* __restrict__ out, int n) {
    int lane = threadIdx.x & 63, wid = threadIdx.x >> 6;
    int d = blockIdx.x * 4 + wid;
    if (d >= n) return;
    float dd = dinv[d];
    float acc = dd * (float)hpre[(size_t)d * 64 + lane];  // self loop
    int s0 = row_ptr[d], s1 = row_ptr[d + 1];
    for (int base = s0; base < s1; base += 64) {
        int j = base + lane;
        int sl = 0;
        float wl = 0.f;
        if (j < s1) { sl = ssorted[j]; wl = dinv[sl]; }
        int cnt = min(64, s1 - base);
        int i = 0;
        for (; i + 4 <= cnt; i += 4) {
            int a0 = __shfl(sl, i), a1 = __shfl(sl, i + 1);
            int a2 = __shfl(sl, i + 2), a3 = __shfl(sl, i + 3);
            float w0 = __shfl(wl, i), w1 = __shfl(wl, i + 1);
            float w2 = __shfl(wl, i + 2), w3 = __shfl(wl, i + 3);
            float v0 = (float)hpre[(size_t)a0 * 64 + lane];
            float v1 = (float)hpre[(size_t)a1 * 64 + lane];
            float v2 = (float)hpre[(size_t)a2 * 64 + lane];
            float v3 = (float)hpre[(size_t)a3 * 64 + lane];
            acc += w0 * v0; acc += w1 * v1; acc += w2 * v2; acc += w3 * v3;
        }
        for (; i < cnt; i++) {
            int a = __shfl(sl, i);
            float w = __shfl(wl, i);
            acc += w * (float)hpre[(size_t)a * 64 + lane];
        }
    }
    float val = dd * acc;
    if (RELU_BIAS) val = fmaxf(val + bias[lane], 0.f);
    out[(size_t)d * 64 + lane] = (f16)val;
}

// ---------------- fused middle (MFMA): 64 nodes per block; h1/hd are f16 ----------------

#define MB 64
__global__ __launch_bounds__(256) void k_mid(const f16* __restrict__ h1,
                                             const float* __restrict__ Wz, const float* __restrict__ bz,
                                             const float* __restrict__ Wd, const float* __restrict__ bd,
                                             const float* __restrict__ Wc, const float* __restrict__ bc,
                                             f16* __restrict__ hd_ws,
                                             float* __restrict__ z_out, float* __restrict__ pred_out,
                                             int n) {
    __shared__ __attribute__((aligned(16))) f16 Ah[64 * 72];
    __shared__ __attribute__((aligned(16))) f16 Zh[64 * 40];
    __shared__ __attribute__((aligned(16))) f16 WzB[2 * 2 * 64 * 8];
    __shared__ __attribute__((aligned(16))) f16 WdB[4 * 64 * 8];
    __shared__ float Wcs[32 * 4];
    __shared__ float bzs[32], bds[64], bcs[4];
    int tid = threadIdx.x;
    int row0 = blockIdx.x * MB;

    for (int i = tid; i < 2048; i += 256) {
        int k = i >> 5, c = i & 31;
        int ks = k >> 5, q = (k >> 3) & 3, j = k & 7;
        int t = c >> 4, ln = q * 16 + (c & 15);
        WzB[((t * 2 + ks) * 64 + ln) * 8 + j] = (f16)Wz[i];
    }
    for (int i = tid; i < 2048; i += 256) {
        int k = i >> 6, c = i & 63;
        int q = k >> 3, j = k & 7;
        int t = c >> 4, ln = q * 16 + (c & 15);
        WdB[(t * 64 + ln) * 8 + j] = (f16)Wd[i];
    }
    if (tid < 96) Wcs[(tid / 3) * 4 + (tid % 3)] = Wc[tid];
    if (tid < 32) bzs[tid] = bz[tid];
    if (tid < 64) bds[tid] = bd[tid];
    if (tid < 3)  bcs[tid] = bc[tid];
    for (int i = tid; i < 1024; i += 256) {
        int r = i >> 4, c4 = (i & 15) * 4;
        half4 hv = {0, 0, 0, 0};
        if (row0 + r < n) hv = *(const half4*)&h1[(size_t)(row0 + r) * 64 + c4];
        *(half4*)&Ah[r * 72 + c4] = hv;
    }
    __syncthreads();

    int lane = tid & 63, w = tid >> 6;
    int m = lane & 15, q = lane >> 4;

    f32x4 za[2];
    za[0] = (f32x4){0.f, 0.f, 0.f, 0.f};
    za[1] = (f32x4){0.f, 0.f, 0.f, 0.f};
#pragma unroll
    for (int ks = 0; ks < 2; ks++) {
        f16x8 a = *(const f16x8*)&Ah[(16 * w + m) * 72 + 32 * ks + 8 * q];
#pragma unroll
        for (int t = 0; t < 2; t++) {
            f16x8 b = *(const f16x8*)&WzB[((t * 2 + ks) * 64 + lane) * 8];
            za[t] = __builtin_amdgcn_mfma_f32_16x16x32_f16(a, b, za[t], 0, 0, 0);
        }
    }
#pragma unroll
    for (int t = 0; t < 2; t++) {
        float bj = bzs[16 * t + m];
#pragma unroll
        for (int r = 0; r < 4; r++) {
            int node = 16 * w + 4 * q + r;
            float zv = za[t][r] + bj;
            Zh[node * 40 + 16 * t + m] = (f16)zv;
            if (row0 + node < n) z_out[(size_t)(row0 + node) * 32 + 16 * t + m] = zv;
        }
    }
    __syncthreads();

    f16x8 a2 = *(const f16x8*)&Zh[(16 * w + m) * 40 + 8 * q];
    f32x4 hb[4];
#pragma unroll
    for (int t = 0; t < 4; t++) {
        f16x8 b = *(const f16x8*)&WdB[(t * 64 + lane) * 8];
        f32x4 zero = (f32x4){0.f, 0.f, 0.f, 0.f};
        hb[t] = __builtin_amdgcn_mfma_f32_16x16x32_f16(a2, b, zero, 0, 0, 0);
    }
#pragma unroll
    for (int t = 0; t < 4; t++) {
        float bf = bds[16 * t + m];
#pragma unroll
        for (int r = 0; r < 4; r++) {
            int node = 16 * w + 4 * q + r;
            if (row0 + node < n)
                hd_ws[(size_t)(row0 + node) * 64 + 16 * t + m] = (f16)fmaxf(hb[t][r] + bf, 0.f);
        }
    }

    if (tid < 64) {
        int node = tid;
        float pa = bcs[0], pb = bcs[1], pc = bcs[2];
        for (int k = 0; k < 32; k++) {
            float zv = (float)Zh[node * 40 + k];
            pa += zv * Wcs[k * 4 + 0];
            pb += zv * Wcs[k * 4 + 1];
            pc += zv * Wcs[k * 4 + 2];
        }
        if (row0 + node < n) {
            pred_out[(size_t)(row0 + node) * 3 + 0] = pa;
            pred_out[(size_t)(row0 + node) * 3 + 1] = pb;
            pred_out[(size_t)(row0 + node) * 3 + 2] = pc;
        }
    }
}

// ---------------- GEMM5 (MFMA): x_recon[n,256] = p2[n,64] @ W_dec_gnn[64,256] + b ---------

#define G5_R 64
__global__ __launch_bounds__(256) void k_gemm5(const f16* __restrict__ A,
                                               const float* __restrict__ W,
                                               const float* __restrict__ bias,
                                               float* __restrict__ out, int n) {
    __shared__ __attribute__((aligned(16))) f16 WB[16 * 2 * 64 * 8];  // 32 KB
    __shared__ __attribute__((aligned(16))) f16 Ah[64 * 72];          // 9 KB
    __shared__ float bs[256];
    int tid = threadIdx.x;
    int row0 = blockIdx.x * G5_R;

    for (int i = tid; i < 4096; i += 256) {
        int k = i >> 6, c4 = (i & 63) * 4;
        float4 w = *(const float4*)&W[k * 256 + c4];
        int ks = k >> 5, q = (k >> 3) & 3, j = k & 7;
        int t = c4 >> 4;
        int base = ((t * 2 + ks) * 64 + q * 16 + (c4 & 15)) * 8 + j;
        WB[base + 0]  = (f16)w.x;
        WB[base + 8]  = (f16)w.y;
        WB[base + 16] = (f16)w.z;
        WB[base + 24] = (f16)w.w;
    }
    for (int i = tid; i < 1024; i += 256) {
        int r = i >> 4, c4 = (i & 15) * 4;
        half4 hv = {0, 0, 0, 0};
        if (row0 + r < n) hv = *(const half4*)&A[(size_t)(row0 + r) * 64 + c4];
        *(half4*)&Ah[r * 72 + c4] = hv;
    }
    bs[tid] = bias[tid];
    __syncthreads();

    int lane = tid & 63, w = tid >> 6;
    int m = lane & 15, q = lane >> 4;

    f16x8 a0 = *(const f16x8*)&Ah[(16 * w + m) * 72 + 0 + 8 * q];
    f16x8 a1 = *(const f16x8*)&Ah[(16 * w + m) * 72 + 32 + 8 * q];

    int gr0 = row0 + 16 * w + 4 * q;
    bool full = (gr0 + 3 < n);
#pragma unroll 4
    for (int t = 0; t < 16; t++) {
        f32x4 acc = (f32x4){0.f, 0.f, 0.f, 0.f};
        f16x8 b0 = *(const f16x8*)&WB[((t * 2 + 0) * 64 + lane) * 8];
        acc = __builtin_amdgcn_mfma_f32_16x16x32_f16(a0, b0, acc, 0, 0, 0);
        f16x8 b1 = *(const f16x8*)&WB[((t * 2 + 1) * 64 + lane) * 8];
        acc = __builtin_amdgcn_mfma_f32_16x16x32_f16(a1, b1, acc, 0, 0, 0);
        float bf = bs[16 * t + m];
        if (full) {
#pragma unroll
            for (int r = 0; r < 4; r++)
                out[(size_t)(gr0 + r) * 256 + 16 * t + m] = acc[r] + bf;
        } else {
#pragma unroll
            for (int r = 0; r < 4; r++)
                if (gr0 + r < n) out[(size_t)(gr0 + r) * 256 + 16 * t + m] = acc[r] + bf;
        }
    }
}

// ---------------- launch ----------------

extern "C" void kernel_launch(void* const* d_in, const int* in_sizes, int n_in,
                              void* d_out, int out_size, void* d_ws, size_t ws_size,
                              hipStream_t stream) {
    const float* x    = (const float*)d_in[0];
    const int*   ei   = (const int*)d_in[1];
    const float* Wenc = (const float*)d_in[3];
    const float* benc = (const float*)d_in[4];
    const float* Wz   = (const float*)d_in[5];
    const float* bz   = (const float*)d_in[6];
    const float* Wd   = (const float*)d_in[7];
    const float* bd   = (const float*)d_in[8];
    const float* Wdec = (const float*)d_in[9];
    const float* bdec = (const float*)d_in[10];
    const float* Wc   = (const float*)d_in[11];
    const float* bc   = (const float*)d_in[12];

    int n = in_sizes[0] / 256;
    int E = in_sizes[1] / 2;
    const int* src = ei;
    const int* dst = ei + E;

    int nbk = (n + BKT_SZ - 1) >> BKT_SH;
    int nbin = (E + EB - 1) / EB;

    char* w = (char*)d_ws;
    size_t off = 0;
    auto alloc = [&](size_t bytes) {
        void* p = w + off;
        off = (off + bytes + 255) & ~(size_t)255;
        return p;
    };
    int*      row_ptr = (int*)alloc(sizeof(int) * (n + 1));
    int*      ssorted = (int*)alloc(sizeof(int) * E);
    unsigned* ebuf    = (unsigned*)alloc(sizeof(unsigned) * E);
    float*    dinv    = (float*)alloc(sizeof(float) * n);
    int*      gcnt    = (int*)alloc(sizeof(int) * 128);
    int*      bbase   = (int*)alloc(sizeof(int) * 128);
    int*      bcur    = (int*)alloc(sizeof(int) * 128);
    f16*      bufA    = (f16*)alloc(sizeof(f16) * (size_t)n * 64);  // h1pre -> hd
    f16*      bufB    = (f16*)alloc(sizeof(f16) * (size_t)n * 64);  // h1 -> p2
    (void)ws_size; (void)n_in; (void)out_size;

    float* out_xr = (float*)d_out;
    float* out_z  = out_xr + (size_t)n * 256;
    float* out_p  = out_z + (size_t)n * 32;

    // CSR build (bucketed counting sort)
    k_zero_int<<<dim3(1), dim3(128), 0, stream>>>(gcnt, 128);
    k_bhist<<<dim3(nbin), dim3(256), 0, stream>>>(dst, E, nbk, gcnt);
    k_bscan<<<dim3(1), dim3(256), 0, stream>>>(gcnt, nbk, E, n, bbase, bcur, row_ptr);
    k_binA<<<dim3(nbin), dim3(256), 0, stream>>>(src, dst, E, bcur, ebuf);
    k_csr<<<dim3(nbk), dim3(256), 0, stream>>>(ebuf, bbase, gcnt, n, row_ptr, dinv, ssorted);

    // encoder: bufA = x @ W_enc (f16) ; bufB = relu(P bufA + b_enc) (f16)
    k_gemm1<<<dim3((n + G1M_R - 1) / G1M_R), dim3(256), 0, stream>>>(x, Wenc, bufA, n);
    k_prop<true><<<dim3((n + 3) / 4), dim3(256), 0, stream>>>(bufA, row_ptr, ssorted, dinv, benc, bufB, n);

    // middle: z (out), pred (out), hd -> bufA (f16)
    k_mid<<<dim3((n + MB - 1) / MB), dim3(256), 0, stream>>>(bufB, Wz, bz, Wd, bd, Wc, bc,
                                                             bufA, out_z, out_p, n);

    // decoder (reassociated): bufB = P bufA (f16) ; x_recon = bufB @ W_dec + b_dec
    k_prop<false><<<dim3((n + 3) / 4), dim3(256), 0, stream>>>(bufA, row_ptr, ssorted, dinv, benc, bufB, n);
    k_gemm5<<<dim3((n + G5_R - 1) / G5_R), dim3(256), 0, stream>>>(bufB, Wdec, bdec, out_xr, n);
}